// Round 16
// baseline (111.509 us; speedup 1.0000x reference)
//
#include <hip/hip_runtime.h>
#include <stdint.h>

#define BATCH 8
#define NANCH 32768
#define NCLS 81
#define PRE_K 2048
#define PK1 256
#define CAP 1024
#define MAX_OUT 200
#define SCORE_TH 0.05f
#define T0 0.9998f

typedef uint32_t u32;
typedef uint64_t u64;
typedef uint8_t u8;

__device__ __forceinline__ u32 f2sort(float f) {
  u32 u = __float_as_uint(f);
  return (u & 0x80000000u) ? ~u : (u | 0x80000000u);
}
__device__ __forceinline__ float sort2f(u32 u) {
  u = (u & 0x80000000u) ? (u & 0x7FFFFFFFu) : ~u;
  return __uint_as_float(u);
}
__device__ __forceinline__ u64 shfl_xor64(u64 x, int m) {
  u32 lo = (u32)__shfl_xor((int)(u32)x, m);
  u32 hi = (u32)__shfl_xor((int)(u32)(x >> 32), m);
  return ((u64)hi << 32) | lo;
}

// ---------------- kernel 1: score + candidate pre-filter -------------------
// Candidate key = (hi<<32) | ((0x7FFF-n)<<7) | cat : full-u64 order == score
// desc, then anchor asc (cat bits below n bits can never decide a compare).
__global__ __launch_bounds__(256) void k_score(const float* __restrict__ confs,
                                               u32* __restrict__ keyhi,
                                               u8* __restrict__ cats,
                                               u64* __restrict__ candBuf,
                                               u32* __restrict__ candCnt,
                                               u32* __restrict__ gNval) {
  __shared__ float st[64 * NCLS];
  __shared__ u32 outh[64];
  __shared__ u8 outc[64];
  int tid = threadIdx.x;
  const float4* src = (const float4*)confs + (size_t)blockIdx.x * (64 * NCLS / 4);
  float4* dst = (float4*)st;
  for (int idx = tid; idx < 64 * NCLS / 4; idx += 256) dst[idx] = src[idx];
  __syncthreads();

  int a = tid >> 2, s = tid & 3;
  const float* row = st + a * NCLS;
  int c0 = s * 20;
  int cnt = (s == 3) ? 21 : 20;
  u64 key = 0;
  for (int k = 0; k < cnt; ++k) {
    int c = c0 + k;
    u64 k2 = ((u64)__float_as_uint(row[c]) << 7) | (u32)(127 - c);
    if (k2 > key) key = k2;
  }
  u64 o = __shfl_xor(key, 1); if (o > key) key = o;
  o = __shfl_xor(key, 2); if (o > key) key = o;
  if (s == 0) {
    float v = __uint_as_float((u32)(key >> 7));
    int c = 127 - (int)(key & 127);
    bool valid = (v > SCORE_TH) && (c != 0);
    float sc = valid ? v : -1.0f;
    outh[a] = f2sort(sc);
    outc[a] = (u8)c;
  }
  __syncthreads();
  if (tid < 64) {  // wave 0 only: full 64-lane ballots are safe
    int g = blockIdx.x * 64 + tid;
    u32 h = outh[tid];
    u8 c = outc[tid];
    keyhi[g] = h;
    cats[g] = c;
    int b = blockIdx.x >> 9;            // 512 blocks per batch
    u32 n = (u32)(g & (NANCH - 1));
    // valid = positive score key (top bit set after f2sort)
    u64 vm = __ballot((h & 0x80000000u) != 0);
    if (tid == 0 && vm) atomicAdd(&gNval[b], (u32)__popcll(vm));
    // candidate pre-filter
    const u32 H0 = f2sort(T0);
    bool q = h > H0;
    u64 qm = __ballot(q);
    u32 base = 0;
    if (tid == 0 && qm) base = atomicAdd(&candCnt[b], (u32)__popcll(qm));
    base = __shfl(base, 0);
    if (q) {
      u32 pos = base + (u32)__popcll(qm & ((1ull << tid) - 1));
      if (pos < CAP) {
        u64 k = ((u64)h << 32) | ((u64)(0x7FFFu - n) << 7) | (u64)c;
        candBuf[(size_t)b * CAP + pos] = k;
      }
    }
  }
}

// -------- wave-scan digit finder ---------
template <int B>
__device__ void scan_digit_fast(const u32* gh, int need, u32* sbuf,
                                int tid, int* D, int* NO) {
  const int CS = B / 256;
  if (tid < 256) {
    int hi = B - 1 - tid * CS;
    u32 s = 0;
    #pragma unroll 4
    for (int k = 0; k < CS; ++k) s += gh[hi - k];
    sbuf[tid] = s;
  }
  __syncthreads();
  if (tid < 64) {
    u32 v0 = sbuf[tid * 4], v1 = sbuf[tid * 4 + 1];
    u32 v2 = sbuf[tid * 4 + 2], v3 = sbuf[tid * 4 + 3];
    u32 loc = v0 + v1 + v2 + v3;
    u32 inc = loc;
    #pragma unroll
    for (int off = 1; off < 64; off <<= 1) {
      u32 ov = __shfl_up(inc, off);
      if (tid >= off) inc += ov;
    }
    u32 exc = inc - loc;
    if (exc < (u32)need && inc >= (u32)need) {
      int acc = (int)exc;
      u32 vs[4] = {v0, v1, v2, v3};
      #pragma unroll
      for (int c = 0; c < 4; ++c) {
        if (acc + (int)vs[c] >= need) {
          int h2 = B - 1 - (tid * 4 + c) * CS;
          for (int k = 0; k < CS; ++k) {
            u32 h = gh[h2 - k];
            acc += (int)h;
            if (acc >= need) {
              sbuf[256] = (u32)(h2 - k);
              sbuf[257] = (u32)(need - (acc - (int)h));
              break;
            }
          }
          break;
        }
        acc += (int)vs[c];
      }
    }
  }
  __syncthreads();
  *D = (int)sbuf[256];
  *NO = (int)sbuf[257];
  __syncthreads();
}

// ======== kernel 2: candidate top-256 + reg-sort + mask + scan + out =======
// All candidate his share top-12 bits (T0 < score < 1.0), so the 12-bit
// mid-digit (hi bits [19:8]) hist is order-correct; ties resolved full-u64.
__global__ __launch_bounds__(1024) void k_sel(const u64* __restrict__ candBuf,
                                              const u32* __restrict__ candCnt,
                                              const u32* __restrict__ gNval,
                                              const float* __restrict__ boxes,
                                              float* __restrict__ out,
                                              u32* __restrict__ gFlag) {
  int b = blockIdx.x;
  int tid = threadIdx.x;
  int lane = tid & 63;
  __shared__ u32 hist[4096];
  __shared__ u32 sbuf[258];
  __shared__ u64 selk[PK1];
  __shared__ u64 ties[128];
  __shared__ u32 s_cnt, s_tcnt, s_cand, s_nv;
  __shared__ int s_kc;
  __shared__ u32 s_ok;
  __shared__ u32 slo_s[PK1];
  __shared__ float ssc_s[PK1];
  __shared__ float4 sbo_s[PK1];
  __shared__ float4 sorg_s[PK1];
  __shared__ float sar_s[PK1];
  __shared__ u64 mk[PK1][4];
  __shared__ int keptI[MAX_OUT];

  if (tid == 0) {
    s_cand = candCnt[b];
    s_nv = gNval[b];
    s_cnt = 0;
    s_tcnt = 0;
  }
  for (int i = tid; i < 4096; i += 1024) hist[i] = 0;
  __syncthreads();

  u32 cnt = s_cand;
  if (cnt < PK1 || cnt > CAP) {   // pre-filter band miss -> exact fallback
    if (tid == 0) gFlag[b] = 0;
    return;
  }

  u64 myk = (tid < (int)cnt) ? candBuf[(size_t)b * CAP + tid] : 0;
  u32 dig = (u32)(myk >> 40) & 0xFFF;   // hi bits [19:8]

  if (tid < (int)cnt) atomicAdd(&hist[dig], 1u);
  __syncthreads();
  int D1, n1;
  scan_digit_fast<4096>(hist, PK1, sbuf, tid, &D1, &n1);
  int need = n1;

  // compaction: strict-greater digit
  {
    bool gt = (tid < (int)cnt) && ((int)dig > D1);
    u64 m = __ballot(gt);
    u32 wbase = 0;
    if (lane == 0 && m) wbase = atomicAdd(&s_cnt, (u32)__popcll(m));
    wbase = __shfl(wbase, 0);
    if (gt) {
      u32 pos = wbase + (u32)__popcll(m & ((1ull << lane) - 1));
      if (pos < PK1) selk[pos] = myk;
    }
    bool te = (tid < (int)cnt) && ((int)dig == D1);
    if (te) {
      u32 tp = atomicAdd(&s_tcnt, 1u);
      if (tp < 128) ties[tp] = myk;
    }
  }
  __syncthreads();

  bool tieOK = (s_tcnt <= 128u);
  {
    int nt = (int)s_tcnt; if (nt > 128) nt = 128;
    int base = (int)s_cnt;  // == PK1 - need when tieOK
    if (tid < nt) {
      u64 my = ties[tid];
      int r = 0;
      for (int j = 0; j < nt; ++j) r += (ties[j] > my);
      if (r < need && base + r < PK1) selk[base + r] = my;
    }
  }
  __syncthreads();

  // ---- in-register bitonic sort of 256 keys in wave 0 ---------------------
  if (tid < 64) {
    u64 v0 = selk[lane], v1 = selk[64 + lane], v2 = selk[128 + lane], v3 = selk[192 + lane];

#define CAS_REG(A, B, UP) { u64 ta = A, tb = B; if ((ta > tb) == (UP)) { A = tb; B = ta; } }
#define CAS_SHF(R, J, UP) { u64 o = shfl_xor64(R, (J)); bool tm = (((lane & (J)) == 0) == (UP)); \
                            u64 mn = (o < R) ? o : R; u64 mx = (o < R) ? R : o; R = tm ? mn : mx; }
    #pragma unroll
    for (int k = 2; k <= 32; k <<= 1) {
      #pragma unroll
      for (int j = k >> 1; j > 0; j >>= 1) {
        bool u0 = (lane & k) == 0;
        CAS_SHF(v0, j, u0) CAS_SHF(v1, j, u0) CAS_SHF(v2, j, u0) CAS_SHF(v3, j, u0)
      }
    }
    #pragma unroll
    for (int j = 32; j > 0; j >>= 1) {
      CAS_SHF(v0, j, true) CAS_SHF(v1, j, false) CAS_SHF(v2, j, true) CAS_SHF(v3, j, false)
    }
    CAS_REG(v0, v1, true) CAS_REG(v2, v3, false)
    #pragma unroll
    for (int j = 32; j > 0; j >>= 1) {
      CAS_SHF(v0, j, true) CAS_SHF(v1, j, true) CAS_SHF(v2, j, false) CAS_SHF(v3, j, false)
    }
    CAS_REG(v0, v2, true) CAS_REG(v1, v3, true)
    CAS_REG(v0, v1, true) CAS_REG(v2, v3, true)
    #pragma unroll
    for (int j = 32; j > 0; j >>= 1) {
      CAS_SHF(v0, j, true) CAS_SHF(v1, j, true) CAS_SHF(v2, j, true) CAS_SHF(v3, j, true)
    }
#undef CAS_REG
#undef CAS_SHF

    #pragma unroll
    for (int r = 0; r < 4; ++r) {
      u64 key = (r == 0) ? v0 : (r == 1) ? v1 : (r == 2) ? v2 : v3;
      int d = 255 - (r * 64 + lane);   // descending rank
      slo_s[d] = (u32)key;
      ssc_s[d] = sort2f((u32)(key >> 32));
    }
  }
  __syncthreads();

  // ---- gather boxes in sorted order (n, cat unpacked from key) ------------
  if (tid < PK1) {
    u32 lo = slo_s[tid];
    u32 n = 0x7FFFu - ((lo >> 7) & 0x7FFFu);
    int cat = (int)(lo & 0x7Fu);
    const float* bp = boxes + ((size_t)b * NANCH + n) * 4;
    float4 ob = make_float4(bp[0], bp[1], bp[2], bp[3]);
    float off = 2.0f * (float)cat;
    float4 obo = make_float4(ob.x + off, ob.y + off, ob.z + off, ob.w + off);
    sorg_s[tid] = ob;
    sbo_s[tid] = obo;
    sar_s[tid] = fmaxf(obo.z - obo.x, 0.0f) * fmaxf(obo.w - obo.y, 0.0f);
  }
  __syncthreads();

  // ---- 256x256 mask, column-swizzled ------------------------------------
  {
    int i = tid >> 2, w = tid & 3;
    float4 bi = sbo_s[i];
    float ai = sar_s[i];
    u64 word = 0;
    int j0 = w * 64, wsw = w << 1;
    for (int jj = 0; jj < 64; ++jj) {
      int jp = jj ^ wsw;
      float4 bj = sbo_s[j0 + jp];
      float lx = fmaxf(bi.x, bj.x), ly = fmaxf(bi.y, bj.y);
      float rx = fminf(bi.z, bj.z), ry = fminf(bi.w, bj.w);
      float iw = fmaxf(rx - lx, 0.0f), ih = fmaxf(ry - ly, 0.0f);
      float inter = iw * ih;
      float uni = fmaxf(ai + sar_s[j0 + jp] - inter, 1e-9f);
      if (inter > 0.5f * uni) word |= (1ull << jp);
    }
    mk[i][w] = word;
  }
  __syncthreads();

  // ---- greedy scan, wave 0, 8-deep register prefetch ----------------------
  if (tid < 64) {
    bool l4 = lane < 4;
    u64 remv = 0;
    int kcnt = 0;
    u64 m0=0,m1=0,m2=0,m3=0,m4=0,m5=0,m6=0,m7=0;
    float s0, s1, s2, s3, s4, s5, s6, s7;
    if (l4) {
      m0 = mk[0][lane]; m1 = mk[1][lane]; m2 = mk[2][lane]; m3 = mk[3][lane];
      m4 = mk[4][lane]; m5 = mk[5][lane]; m6 = mk[6][lane]; m7 = mk[7][lane];
    }
    s0 = ssc_s[0]; s1 = ssc_s[1]; s2 = ssc_s[2]; s3 = ssc_s[3];
    s4 = ssc_s[4]; s5 = ssc_s[5]; s6 = ssc_s[6]; s7 = ssc_s[7];

#define PROC(D)                                                       \
    {                                                                 \
      int i = base8 + (D);                                            \
      u64 wb = __shfl(remv, i >> 6);                                  \
      bool sup = (wb >> (i & 63)) & 1ull;                             \
      if (!sup && s##D > SCORE_TH) {                                  \
        if (lane == 0 && kcnt < MAX_OUT) keptI[kcnt] = i;             \
        if (l4) remv |= m##D;                                         \
        kcnt++;                                                       \
      }                                                               \
    }

    for (int base8 = 0; base8 < PK1; base8 += 8) {
      u64 t0=0,t1=0,t2=0,t3=0,t4=0,t5=0,t6=0,t7=0;
      float u0=0,u1=0,u2=0,u3=0,u4=0,u5=0,u6=0,u7=0;
      if (base8 + 8 < PK1) {
        int nb = base8 + 8;
        if (l4) {
          t0 = mk[nb+0][lane]; t1 = mk[nb+1][lane]; t2 = mk[nb+2][lane]; t3 = mk[nb+3][lane];
          t4 = mk[nb+4][lane]; t5 = mk[nb+5][lane]; t6 = mk[nb+6][lane]; t7 = mk[nb+7][lane];
        }
        u0 = ssc_s[nb+0]; u1 = ssc_s[nb+1]; u2 = ssc_s[nb+2]; u3 = ssc_s[nb+3];
        u4 = ssc_s[nb+4]; u5 = ssc_s[nb+5]; u6 = ssc_s[nb+6]; u7 = ssc_s[nb+7];
      }
      PROC(0) PROC(1) PROC(2) PROC(3) PROC(4) PROC(5) PROC(6) PROC(7)
      m0=t0; m1=t1; m2=t2; m3=t3; m4=t4; m5=t5; m6=t6; m7=t7;
      s0=u0; s1=u1; s2=u2; s3=u3; s4=u4; s5=u5; s6=u6; s7=u7;
      if (kcnt >= MAX_OUT) break;
    }
#undef PROC

    if (lane == 0) {
      s_kc = kcnt < MAX_OUT ? kcnt : MAX_OUT;
      u32 ok = ((kcnt >= MAX_OUT) || (s_nv <= PK1)) && tieOK;
      s_ok = ok;
      gFlag[b] = ok;
    }
  }
  __syncthreads();

  if (!s_ok) return;  // fallback path produces the output

  int kc = s_kc;
  float* out5 = out;
  float* ocat = out + BATCH * MAX_OUT * 5;
  for (int r = tid; r < MAX_OUT; r += 1024) {
    float* p = out5 + ((size_t)(b * MAX_OUT + r)) * 5;
    if (r < kc) {
      int i = keptI[r];
      float4 ob = sorg_s[i];
      p[0] = ob.x; p[1] = ob.y; p[2] = ob.z; p[3] = ob.w; p[4] = ssc_s[i];
      ocat[b * MAX_OUT + r] = (float)(slo_s[i] & 0x7Fu);
    } else {
      p[0] = 0.0f; p[1] = 0.0f; p[2] = 0.0f; p[3] = 0.0f; p[4] = 0.0f;
      ocat[b * MAX_OUT + r] = 0.0f;
    }
  }
}

// ======== FALLBACK pipeline (exact 2048 path, gated on !gFlag) =============
__global__ __launch_bounds__(1024) void k_sel2048(const u32* __restrict__ keyhi,
                                                  const u8* __restrict__ cats,
                                                  const float* __restrict__ boxes,
                                                  const u32* __restrict__ gFlag,
                                                  float4* __restrict__ candOff,
                                                  float4* __restrict__ candOrig,
                                                  float* __restrict__ candScore,
                                                  int* __restrict__ candCat) {
  int b = blockIdx.x;
  if (gFlag[b]) return;
  int tid = threadIdx.x;
  int lane = tid & 63;
  __shared__ u32 hist[4096];
  __shared__ u32 sbuf[258];
  __shared__ u64 selk[PRE_K];
  __shared__ u64 ties[128];
  __shared__ u32 s_cnt, s_tcnt;

  const uint4* bh4 = (const uint4*)(keyhi + (size_t)b * NANCH);
  uint4 hk[8];
  #pragma unroll
  for (int j = 0; j < 8; ++j) hk[j] = bh4[tid + j * 1024];

  if (tid == 0) { s_cnt = 0; s_tcnt = 0; }
  for (int i = tid; i < 4096; i += 1024) hist[i] = 0;
  __syncthreads();

#define ELEM(j, c) ((c) == 0 ? hk[j].x : (c) == 1 ? hk[j].y : (c) == 2 ? hk[j].z : hk[j].w)
  #pragma unroll
  for (int j = 0; j < 8; ++j) {
    #pragma unroll
    for (int c = 0; c < 4; ++c) {
      u32 d = ELEM(j, c) >> 24;
      u64 todo = ~0ull;
      while (todo) {
        int src = __ffsll((unsigned long long)todo) - 1;
        u32 dd = __shfl(d, src);
        u64 match = __ballot(d == dd);
        if (lane == src) atomicAdd(&hist[dd], (u32)__popcll(match));
        todo &= ~match;
      }
    }
  }
  __syncthreads();
  int D1, n1;
  scan_digit_fast<256>(hist, PRE_K, sbuf, tid, &D1, &n1);

  for (int i = tid; i < 4096; i += 1024) hist[i] = 0;
  __syncthreads();
  u32 p1 = (u32)D1;
  #pragma unroll
  for (int j = 0; j < 8; ++j) {
    #pragma unroll
    for (int c = 0; c < 4; ++c) {
      u32 h = ELEM(j, c);
      if ((h >> 24) == p1) atomicAdd(&hist[(h >> 12) & 0xFFF], 1u);
    }
  }
  __syncthreads();
  int D2, n2;
  scan_digit_fast<4096>(hist, n1, sbuf, tid, &D2, &n2);

  for (int i = tid; i < 4096; i += 1024) hist[i] = 0;
  __syncthreads();
  u32 p2 = (p1 << 12) | (u32)D2;
  #pragma unroll
  for (int j = 0; j < 8; ++j) {
    #pragma unroll
    for (int c = 0; c < 4; ++c) {
      u32 h = ELEM(j, c);
      if ((h >> 12) == p2) atomicAdd(&hist[h & 0xFFF], 1u);
    }
  }
  __syncthreads();
  int D3, n3;
  scan_digit_fast<4096>(hist, n2, sbuf, tid, &D3, &n3);

  u32 S32 = (p2 << 12) | (u32)D3;
  int need3 = n3;

  #pragma unroll
  for (int j = 0; j < 8; ++j) {
    #pragma unroll
    for (int c = 0; c < 4; ++c) {
      u32 h = ELEM(j, c);
      u32 n = (u32)(4 * tid + 4096 * j + c);
      u64 k = ((u64)h << 32) | (u64)(0xFFFFFFFFu - n);
      bool gt = h > S32;
      u64 m = __ballot(gt);
      u32 wbase = 0;
      if (lane == 0 && m) wbase = atomicAdd(&s_cnt, (u32)__popcll(m));
      wbase = __shfl(wbase, 0);
      if (gt) {
        u32 pos = wbase + (u32)__popcll(m & ((1ull << lane) - 1));
        if (pos < PRE_K) selk[pos] = k;
      }
      if (h == S32) {
        u32 tp = atomicAdd(&s_tcnt, 1u);
        if (tp < 128) ties[tp] = k;
      }
    }
  }
#undef ELEM
  __syncthreads();

  int nt = (int)s_tcnt; if (nt > 128) nt = 128;
  int base = (int)s_cnt;
  if (tid < nt) {
    u64 my = ties[tid];
    int r = 0;
    for (int j = 0; j < nt; ++j) r += (ties[j] > my);
    if (r < need3 && base + r < PRE_K) selk[base + r] = my;
  }
  __syncthreads();

  for (int k = 2; k <= PRE_K; k <<= 1) {
    for (int j = k >> 1; j > 0; j >>= 1) {
      for (int idx = tid; idx < PRE_K; idx += 1024) {
        int ixj = idx ^ j;
        if (ixj > idx) {
          u64 a = selk[idx], c = selk[ixj];
          bool up = ((idx & k) == 0);
          if ((a > c) == up) { selk[idx] = c; selk[ixj] = a; }
        }
      }
      __syncthreads();
    }
  }

  for (int r = tid; r < PRE_K; r += 1024) {
    u64 my = selk[PRE_K - 1 - r];
    u32 n = 0xFFFFFFFFu - (u32)(my & 0xFFFFFFFFu);
    float s = sort2f((u32)(my >> 32));
    int cat = (int)cats[(size_t)b * NANCH + n];
    const float* bp = boxes + ((size_t)b * NANCH + n) * 4;
    float4 ob = make_float4(bp[0], bp[1], bp[2], bp[3]);
    float off = 2.0f * (float)cat;
    float4 obo = make_float4(ob.x + off, ob.y + off, ob.z + off, ob.w + off);
    int o = b * PRE_K + r;
    candOff[o] = obo;
    candOrig[o] = ob;
    candScore[o] = s;
    candCat[o] = cat;
  }
}

__global__ __launch_bounds__(256) void k_mask2048(const float4* __restrict__ candOff,
                                                  const u32* __restrict__ gFlag,
                                                  u64* __restrict__ mask) {
  int b = blockIdx.y;
  if (gFlag[b]) return;
  int tid = threadIdx.x;
  int wave = tid >> 6, lane = tid & 63;
  __shared__ float4 sb[PRE_K];
  __shared__ float sarea[PRE_K];
  for (int j = tid; j < PRE_K; j += 256) {
    float4 v = candOff[b * PRE_K + j];
    sb[j] = v;
    sarea[j] = fmaxf(v.z - v.x, 0.0f) * fmaxf(v.w - v.y, 0.0f);
  }
  __syncthreads();

  int gw = blockIdx.x * 4 + wave;
  for (int k = 0; k < PRE_K / 256; ++k) {
    int i = gw + 256 * k;
    float4 bi = sb[i];
    float ai = sarea[i];
    int c0 = i >> 6;
    u64 myword = 0;
    for (int c = c0; c < 32; ++c) {
      float4 bj = sb[c * 64 + lane];
      float aj = sarea[c * 64 + lane];
      float lx = fmaxf(bi.x, bj.x), ly = fmaxf(bi.y, bj.y);
      float rx = fminf(bi.z, bj.z), ry = fminf(bi.w, bj.w);
      float iw = fmaxf(rx - lx, 0.0f), ih = fmaxf(ry - ly, 0.0f);
      float inter = iw * ih;
      float uni = fmaxf(ai + aj - inter, 1e-9f);
      u64 word = __ballot(inter > 0.5f * uni);
      if (lane == c) myword = word;
    }
    if (lane < 32) mask[((size_t)(b * PRE_K + i)) * 32 + lane] = myword;
  }
}

__global__ __launch_bounds__(64) void k_scan2048(const u64* __restrict__ mask,
                                                 const float4* __restrict__ candOrig,
                                                 const float* __restrict__ candScore,
                                                 const int* __restrict__ candCat,
                                                 const u32* __restrict__ gFlag,
                                                 float* __restrict__ out) {
  int b = blockIdx.x;
  if (gFlag[b]) return;
  int tid = threadIdx.x;
  __shared__ float ssc[PRE_K];
  __shared__ int keptI[MAX_OUT];
  for (int j = tid; j < PRE_K; j += 64) ssc[j] = candScore[b * PRE_K + j];
  __syncthreads();

  const u64* mrow = mask + (size_t)b * PRE_K * 32;
  int wsel = tid & 31;
  bool lo32 = tid < 32;
  u64 remv = 0;
  int cnt = 0;

  u64 c0=0,c1=0,c2=0,c3=0,c4=0,c5=0,c6=0,c7=0;
  if (lo32) {
    c0 = mrow[0 * 32 + wsel]; c1 = mrow[1 * 32 + wsel];
    c2 = mrow[2 * 32 + wsel]; c3 = mrow[3 * 32 + wsel];
    c4 = mrow[4 * 32 + wsel]; c5 = mrow[5 * 32 + wsel];
    c6 = mrow[6 * 32 + wsel]; c7 = mrow[7 * 32 + wsel];
  }

#define PROCESS(I, RK)                                   \
  {                                                      \
    u64 wb = __shfl(remv, (I) >> 6);                     \
    bool sup = (wb >> ((I) & 63)) & 1ull;                \
    if (!sup && ssc[I] > SCORE_TH) {                     \
      if (tid == 0 && cnt < MAX_OUT) keptI[cnt] = (I);   \
      if (lo32) remv |= (RK);                            \
      cnt++;                                             \
    }                                                    \
  }

  for (int base = 0; base < PRE_K; base += 8) {
    u64 n0=0,n1=0,n2=0,n3=0,n4=0,n5=0,n6=0,n7=0;
    if (base + 8 < PRE_K && lo32) {
      const u64* nr = mrow + (size_t)(base + 8) * 32 + wsel;
      n0 = nr[0 * 32]; n1 = nr[1 * 32]; n2 = nr[2 * 32]; n3 = nr[3 * 32];
      n4 = nr[4 * 32]; n5 = nr[5 * 32]; n6 = nr[6 * 32]; n7 = nr[7 * 32];
    }
    PROCESS(base + 0, c0); PROCESS(base + 1, c1);
    PROCESS(base + 2, c2); PROCESS(base + 3, c3);
    PROCESS(base + 4, c4); PROCESS(base + 5, c5);
    PROCESS(base + 6, c6); PROCESS(base + 7, c7);
    c0=n0; c1=n1; c2=n2; c3=n3; c4=n4; c5=n5; c6=n6; c7=n7;
    if (cnt >= MAX_OUT) break;
  }
#undef PROCESS

  int kc = cnt < MAX_OUT ? cnt : MAX_OUT;
  __syncthreads();

  float* out5 = out;
  float* ocat = out + BATCH * MAX_OUT * 5;
  for (int r = tid; r < MAX_OUT; r += 64) {
    float* p = out5 + ((size_t)(b * MAX_OUT + r)) * 5;
    if (r < kc) {
      int i = keptI[r];
      float4 ob = candOrig[b * PRE_K + i];
      p[0] = ob.x; p[1] = ob.y; p[2] = ob.z; p[3] = ob.w; p[4] = ssc[i];
      ocat[b * MAX_OUT + r] = (float)candCat[b * PRE_K + i];
    } else {
      p[0] = 0.0f; p[1] = 0.0f; p[2] = 0.0f; p[3] = 0.0f; p[4] = 0.0f;
      ocat[b * MAX_OUT + r] = 0.0f;
    }
  }
}

extern "C" void kernel_launch(void* const* d_in, const int* in_sizes, int n_in,
                              void* d_out, int out_size, void* d_ws, size_t ws_size,
                              hipStream_t stream) {
  const float* boxes = (const float*)d_in[0];
  const float* confs = (const float*)d_in[1];
  float* out = (float*)d_out;
  char* ws = (char*)d_ws;

  const size_t OFF_KHI  = 0;                            // 1 MB
  const size_t OFF_CATS = (size_t)1 << 20;              // 256 KB
  const size_t OFF_ZERO = OFF_CATS + (256u << 10);      // memset region: candCnt[8]+gNval[8]
  const size_t ZERO_END = OFF_ZERO + 128;
  const size_t OFF_FLAG = ZERO_END;                     // 64 B (always written)
  const size_t OFF_CB   = OFF_FLAG + 64;                // 64 KB candidate buffers
  const size_t OFF_COFF = OFF_CB + (size_t)BATCH * CAP * 8;  // 256 KB (fallback)
  const size_t OFF_CORG = OFF_COFF + (256u << 10);      // 256 KB
  const size_t OFF_CSC  = OFF_CORG + (256u << 10);      // 64 KB
  const size_t OFF_CCAT = OFF_CSC + (64u << 10);        // 64 KB
  const size_t OFF_MASK = OFF_CCAT + (64u << 10);       // 4 MB

  u32* keyhi   = (u32*)(ws + OFF_KHI);
  u8* cats     = (u8*)(ws + OFF_CATS);
  u32* candCnt = (u32*)(ws + OFF_ZERO);
  u32* gNval   = (u32*)(ws + OFF_ZERO + 64);
  u32* gFlag   = (u32*)(ws + OFF_FLAG);
  u64* candBuf = (u64*)(ws + OFF_CB);
  float4* cOff = (float4*)(ws + OFF_COFF);
  float4* cOrg = (float4*)(ws + OFF_CORG);
  float* cSc   = (float*)(ws + OFF_CSC);
  int* cCat    = (int*)(ws + OFF_CCAT);
  u64* mask    = (u64*)(ws + OFF_MASK);

  hipMemsetAsync(ws + OFF_ZERO, 0, ZERO_END - OFF_ZERO, stream);

  k_score<<<BATCH * NANCH / 64, 256, 0, stream>>>(confs, keyhi, cats, candBuf, candCnt, gNval);
  k_sel<<<BATCH, 1024, 0, stream>>>(candBuf, candCnt, gNval, boxes, out, gFlag);
  // fallback (exact 2048 path), no-ops when gFlag[b] == 1
  k_sel2048<<<BATCH, 1024, 0, stream>>>(keyhi, cats, boxes, gFlag, cOff, cOrg, cSc, cCat);
  dim3 g3(64, BATCH);
  k_mask2048<<<g3, 256, 0, stream>>>(cOff, gFlag, mask);
  k_scan2048<<<BATCH, 64, 0, stream>>>(mask, cOrg, cSc, cCat, gFlag, out);
}

// Round 17
// 69.896 us; speedup vs baseline: 1.5954x; 1.5954x over previous
//
#include <hip/hip_runtime.h>
#include <stdint.h>

#define BATCH 8
#define NANCH 32768
#define NCLS 81
#define PRE_K 2048
#define PK1 256
#define CAP 1024
#define SLOTS 16
#define MAX_OUT 200
#define SCORE_TH 0.05f
#define T0 0.9998f

typedef uint32_t u32;
typedef uint64_t u64;
typedef uint8_t u8;

__device__ __forceinline__ u32 f2sort(float f) {
  u32 u = __float_as_uint(f);
  return (u & 0x80000000u) ? ~u : (u | 0x80000000u);
}
__device__ __forceinline__ float sort2f(u32 u) {
  u = (u & 0x80000000u) ? (u & 0x7FFFFFFFu) : ~u;
  return __uint_as_float(u);
}
__device__ __forceinline__ u64 shfl_xor64(u64 x, int m) {
  u32 lo = (u32)__shfl_xor((int)(u32)x, m);
  u32 hi = (u32)__shfl_xor((int)(u32)(x >> 32), m);
  return ((u64)hi << 32) | lo;
}

// ---------------- kernel 1: score + ATOMIC-FREE slotted pre-filter ---------
// Candidate key = (hi<<32) | ((0x7FFF-n)<<7) | cat  (u64 order == score desc,
// anchor asc). Each block writes <=16 candidates to its own slots + u8 count.
__global__ __launch_bounds__(256) void k_score(const float* __restrict__ confs,
                                               u32* __restrict__ keyhi,
                                               u8* __restrict__ cats,
                                               u64* __restrict__ candBuf,
                                               u8* __restrict__ cntA) {
  __shared__ float st[64 * NCLS];
  __shared__ u32 outh[64];
  __shared__ u8 outc[64];
  int tid = threadIdx.x;
  const float4* src = (const float4*)confs + (size_t)blockIdx.x * (64 * NCLS / 4);
  float4* dst = (float4*)st;
  for (int idx = tid; idx < 64 * NCLS / 4; idx += 256) dst[idx] = src[idx];
  __syncthreads();

  int a = tid >> 2, s = tid & 3;
  const float* row = st + a * NCLS;
  int c0 = s * 20;
  int cnt = (s == 3) ? 21 : 20;
  u64 key = 0;
  for (int k = 0; k < cnt; ++k) {
    int c = c0 + k;
    u64 k2 = ((u64)__float_as_uint(row[c]) << 7) | (u32)(127 - c);
    if (k2 > key) key = k2;
  }
  u64 o = __shfl_xor(key, 1); if (o > key) key = o;
  o = __shfl_xor(key, 2); if (o > key) key = o;
  if (s == 0) {
    float v = __uint_as_float((u32)(key >> 7));
    int c = 127 - (int)(key & 127);
    bool valid = (v > SCORE_TH) && (c != 0);
    float sc = valid ? v : -1.0f;
    outh[a] = f2sort(sc);
    outc[a] = (u8)c;
  }
  __syncthreads();
  if (tid < 64) {  // wave 0 only
    int g = blockIdx.x * 64 + tid;
    u32 h = outh[tid];
    u8 c = outc[tid];
    keyhi[g] = h;          // kept for exact fallback
    cats[g] = c;
    const u32 H0 = f2sort(T0);
    bool q = h > H0;
    u64 qm = __ballot(q);
    if (q) {
      u32 pos = (u32)__popcll(qm & ((1ull << tid) - 1));
      if (pos < SLOTS) {
        u32 n = (u32)(g & (NANCH - 1));
        u64 k = ((u64)h << 32) | ((u64)(0x7FFFu - n) << 7) | (u64)c;
        candBuf[(size_t)blockIdx.x * SLOTS + pos] = k;
      }
    }
    if (tid == 0) {
      u32 cb = (u32)__popcll(qm);
      cntA[blockIdx.x] = (u8)(cb > 255 ? 255 : cb);
    }
  }
}

// -------- wave-scan digit finder ---------
template <int B>
__device__ void scan_digit_fast(const u32* gh, int need, u32* sbuf,
                                int tid, int* D, int* NO) {
  const int CS = B / 256;
  if (tid < 256) {
    int hi = B - 1 - tid * CS;
    u32 s = 0;
    #pragma unroll 4
    for (int k = 0; k < CS; ++k) s += gh[hi - k];
    sbuf[tid] = s;
  }
  __syncthreads();
  if (tid < 64) {
    u32 v0 = sbuf[tid * 4], v1 = sbuf[tid * 4 + 1];
    u32 v2 = sbuf[tid * 4 + 2], v3 = sbuf[tid * 4 + 3];
    u32 loc = v0 + v1 + v2 + v3;
    u32 inc = loc;
    #pragma unroll
    for (int off = 1; off < 64; off <<= 1) {
      u32 ov = __shfl_up(inc, off);
      if (tid >= off) inc += ov;
    }
    u32 exc = inc - loc;
    if (exc < (u32)need && inc >= (u32)need) {
      int acc = (int)exc;
      u32 vs[4] = {v0, v1, v2, v3};
      #pragma unroll
      for (int c = 0; c < 4; ++c) {
        if (acc + (int)vs[c] >= need) {
          int h2 = B - 1 - (tid * 4 + c) * CS;
          for (int k = 0; k < CS; ++k) {
            u32 h = gh[h2 - k];
            acc += (int)h;
            if (acc >= need) {
              sbuf[256] = (u32)(h2 - k);
              sbuf[257] = (u32)(need - (acc - (int)h));
              break;
            }
          }
          break;
        }
        acc += (int)vs[c];
      }
    }
  }
  __syncthreads();
  *D = (int)sbuf[256];
  *NO = (int)sbuf[257];
  __syncthreads();
}

// ======== kernel 2: slot-gather + top-256 + reg-sort + mask + scan + out ===
__global__ __launch_bounds__(1024) void k_sel(const u64* __restrict__ candBuf,
                                              const u8* __restrict__ cntA,
                                              const float* __restrict__ boxes,
                                              float* __restrict__ out,
                                              u32* __restrict__ gFlag) {
  int b = blockIdx.x;
  int tid = threadIdx.x;
  int lane = tid & 63;
  int wid = tid >> 6;
  __shared__ u32 hist[4096];
  __shared__ u32 sbuf[258];
  __shared__ u64 cand[CAP];     // 8 KB
  __shared__ u64 selk[PK1];
  __shared__ u64 ties[128];
  __shared__ u32 wtot[8], woff[8];
  __shared__ u32 s_cnt, s_tcnt, s_tot, s_bad;
  __shared__ int s_kc;
  __shared__ u32 s_ok;
  __shared__ u32 slo_s[PK1];
  __shared__ float ssc_s[PK1];
  __shared__ float4 sbo_s[PK1];
  __shared__ float4 sorg_s[PK1];
  __shared__ float sar_s[PK1];
  __shared__ u64 mk[PK1][4];
  __shared__ int keptI[MAX_OUT];

  if (tid == 0) { s_cnt = 0; s_tcnt = 0; s_bad = 0; }
  for (int i = tid; i < 4096; i += 1024) hist[i] = 0;
  __syncthreads();

  // ---- gather candidates from per-block slots (512 blocks per batch) ------
  u32 c = 0;
  if (tid < 512) {
    c = (u32)cntA[b * 512 + tid];
    if (c > SLOTS) atomicOr(&s_bad, 1u);   // slot overflow -> fallback
  }
  u32 inc = c;
  #pragma unroll
  for (int off = 1; off < 64; off <<= 1) {
    u32 ov = __shfl_up(inc, off);
    if (lane >= off) inc += ov;
  }
  if (tid < 512 && lane == 63) wtot[wid] = inc;
  __syncthreads();
  if (tid == 0) {
    u32 acc = 0;
    #pragma unroll
    for (int i = 0; i < 8; ++i) { woff[i] = acc; acc += wtot[i]; }
    s_tot = acc;
  }
  __syncthreads();
  if (tid < 512 && c) {
    u32 exc = inc - c + woff[wid];
    u32 cc = c > SLOTS ? SLOTS : c;
    const u64* sp = candBuf + (size_t)(b * 512 + tid) * SLOTS;
    for (u32 k = 0; k < cc; ++k) {
      u32 p = exc + k;
      if (p < CAP) cand[p] = sp[k];
    }
  }
  __syncthreads();

  u32 tot = s_tot;
  if (s_bad || tot < PK1 || tot > CAP) {
    if (tid == 0) gFlag[b] = 0;
    return;
  }

  // ---- 12-bit mid-digit hist (all cand his share top-12 bits) -------------
  u64 myk = (tid < (int)tot) ? cand[tid] : 0;
  u32 dig = (u32)(myk >> 40) & 0xFFF;
  if (tid < (int)tot) atomicAdd(&hist[dig], 1u);
  __syncthreads();
  int D1, n1;
  scan_digit_fast<4096>(hist, PK1, sbuf, tid, &D1, &n1);
  int need = n1;

  // ---- compaction: strict-greater digit -----------------------------------
  {
    bool gt = (tid < (int)tot) && ((int)dig > D1);
    u64 m = __ballot(gt);
    u32 wbase = 0;
    if (lane == 0 && m) wbase = atomicAdd(&s_cnt, (u32)__popcll(m));
    wbase = __shfl(wbase, 0);
    if (gt) {
      u32 pos = wbase + (u32)__popcll(m & ((1ull << lane) - 1));
      if (pos < PK1) selk[pos] = myk;
    }
    bool te = (tid < (int)tot) && ((int)dig == D1);
    if (te) {
      u32 tp = atomicAdd(&s_tcnt, 1u);
      if (tp < 128) ties[tp] = myk;
    }
  }
  __syncthreads();

  bool tieOK = (s_tcnt <= 128u);
  {
    int nt = (int)s_tcnt; if (nt > 128) nt = 128;
    int base = (int)s_cnt;  // == PK1 - need when tieOK
    if (tid < nt) {
      u64 my = ties[tid];
      int r = 0;
      for (int j = 0; j < nt; ++j) r += (ties[j] > my);
      if (r < need && base + r < PK1) selk[base + r] = my;
    }
  }
  __syncthreads();

  // ---- in-register bitonic sort of 256 keys in wave 0 ---------------------
  if (tid < 64) {
    u64 v0 = selk[lane], v1 = selk[64 + lane], v2 = selk[128 + lane], v3 = selk[192 + lane];

#define CAS_REG(A, B, UP) { u64 ta = A, tb = B; if ((ta > tb) == (UP)) { A = tb; B = ta; } }
#define CAS_SHF(R, J, UP) { u64 o = shfl_xor64(R, (J)); bool tm = (((lane & (J)) == 0) == (UP)); \
                            u64 mn = (o < R) ? o : R; u64 mx = (o < R) ? R : o; R = tm ? mn : mx; }
    #pragma unroll
    for (int k = 2; k <= 32; k <<= 1) {
      #pragma unroll
      for (int j = k >> 1; j > 0; j >>= 1) {
        bool u0 = (lane & k) == 0;
        CAS_SHF(v0, j, u0) CAS_SHF(v1, j, u0) CAS_SHF(v2, j, u0) CAS_SHF(v3, j, u0)
      }
    }
    #pragma unroll
    for (int j = 32; j > 0; j >>= 1) {
      CAS_SHF(v0, j, true) CAS_SHF(v1, j, false) CAS_SHF(v2, j, true) CAS_SHF(v3, j, false)
    }
    CAS_REG(v0, v1, true) CAS_REG(v2, v3, false)
    #pragma unroll
    for (int j = 32; j > 0; j >>= 1) {
      CAS_SHF(v0, j, true) CAS_SHF(v1, j, true) CAS_SHF(v2, j, false) CAS_SHF(v3, j, false)
    }
    CAS_REG(v0, v2, true) CAS_REG(v1, v3, true)
    CAS_REG(v0, v1, true) CAS_REG(v2, v3, true)
    #pragma unroll
    for (int j = 32; j > 0; j >>= 1) {
      CAS_SHF(v0, j, true) CAS_SHF(v1, j, true) CAS_SHF(v2, j, true) CAS_SHF(v3, j, true)
    }
#undef CAS_REG
#undef CAS_SHF

    #pragma unroll
    for (int r = 0; r < 4; ++r) {
      u64 key = (r == 0) ? v0 : (r == 1) ? v1 : (r == 2) ? v2 : v3;
      int d = 255 - (r * 64 + lane);   // descending rank
      slo_s[d] = (u32)key;
      ssc_s[d] = sort2f((u32)(key >> 32));
    }
  }
  __syncthreads();

  // ---- gather boxes in sorted order (n, cat unpacked from key) ------------
  if (tid < PK1) {
    u32 lo = slo_s[tid];
    u32 n = 0x7FFFu - ((lo >> 7) & 0x7FFFu);
    int cat = (int)(lo & 0x7Fu);
    const float* bp = boxes + ((size_t)b * NANCH + n) * 4;
    float4 ob = make_float4(bp[0], bp[1], bp[2], bp[3]);
    float off = 2.0f * (float)cat;
    float4 obo = make_float4(ob.x + off, ob.y + off, ob.z + off, ob.w + off);
    sorg_s[tid] = ob;
    sbo_s[tid] = obo;
    sar_s[tid] = fmaxf(obo.z - obo.x, 0.0f) * fmaxf(obo.w - obo.y, 0.0f);
  }
  __syncthreads();

  // ---- 256x256 mask, column-swizzled --------------------------------------
  {
    int i = tid >> 2, w = tid & 3;
    float4 bi = sbo_s[i];
    float ai = sar_s[i];
    u64 word = 0;
    int j0 = w * 64, wsw = w << 1;
    for (int jj = 0; jj < 64; ++jj) {
      int jp = jj ^ wsw;
      float4 bj = sbo_s[j0 + jp];
      float lx = fmaxf(bi.x, bj.x), ly = fmaxf(bi.y, bj.y);
      float rx = fminf(bi.z, bj.z), ry = fminf(bi.w, bj.w);
      float iw = fmaxf(rx - lx, 0.0f), ih = fmaxf(ry - ly, 0.0f);
      float inter = iw * ih;
      float uni = fmaxf(ai + sar_s[j0 + jp] - inter, 1e-9f);
      if (inter > 0.5f * uni) word |= (1ull << jp);
    }
    mk[i][w] = word;
  }
  __syncthreads();

  // ---- greedy scan, wave 0, 8-deep register prefetch ----------------------
  if (tid < 64) {
    bool l4 = lane < 4;
    u64 remv = 0;
    int kcnt = 0;
    u64 m0=0,m1=0,m2=0,m3=0,m4=0,m5=0,m6=0,m7=0;
    float s0, s1, s2, s3, s4, s5, s6, s7;
    if (l4) {
      m0 = mk[0][lane]; m1 = mk[1][lane]; m2 = mk[2][lane]; m3 = mk[3][lane];
      m4 = mk[4][lane]; m5 = mk[5][lane]; m6 = mk[6][lane]; m7 = mk[7][lane];
    }
    s0 = ssc_s[0]; s1 = ssc_s[1]; s2 = ssc_s[2]; s3 = ssc_s[3];
    s4 = ssc_s[4]; s5 = ssc_s[5]; s6 = ssc_s[6]; s7 = ssc_s[7];

#define PROC(D)                                                       \
    {                                                                 \
      int i = base8 + (D);                                            \
      u64 wb = __shfl(remv, i >> 6);                                  \
      bool sup = (wb >> (i & 63)) & 1ull;                             \
      if (!sup && s##D > SCORE_TH) {                                  \
        if (lane == 0 && kcnt < MAX_OUT) keptI[kcnt] = i;             \
        if (l4) remv |= m##D;                                         \
        kcnt++;                                                       \
      }                                                               \
    }

    for (int base8 = 0; base8 < PK1; base8 += 8) {
      u64 t0=0,t1=0,t2=0,t3=0,t4=0,t5=0,t6=0,t7=0;
      float u0=0,u1=0,u2=0,u3=0,u4=0,u5=0,u6=0,u7=0;
      if (base8 + 8 < PK1) {
        int nb = base8 + 8;
        if (l4) {
          t0 = mk[nb+0][lane]; t1 = mk[nb+1][lane]; t2 = mk[nb+2][lane]; t3 = mk[nb+3][lane];
          t4 = mk[nb+4][lane]; t5 = mk[nb+5][lane]; t6 = mk[nb+6][lane]; t7 = mk[nb+7][lane];
        }
        u0 = ssc_s[nb+0]; u1 = ssc_s[nb+1]; u2 = ssc_s[nb+2]; u3 = ssc_s[nb+3];
        u4 = ssc_s[nb+4]; u5 = ssc_s[nb+5]; u6 = ssc_s[nb+6]; u7 = ssc_s[nb+7];
      }
      PROC(0) PROC(1) PROC(2) PROC(3) PROC(4) PROC(5) PROC(6) PROC(7)
      m0=t0; m1=t1; m2=t2; m3=t3; m4=t4; m5=t5; m6=t6; m7=t7;
      s0=u0; s1=u1; s2=u2; s3=u3; s4=u4; s5=u5; s6=u6; s7=u7;
      if (kcnt >= MAX_OUT) break;
    }
#undef PROC

    if (lane == 0) {
      s_kc = kcnt < MAX_OUT ? kcnt : MAX_OUT;
      u32 ok = (kcnt >= MAX_OUT) && tieOK;   // kept<200 -> exact fallback
      s_ok = ok;
      gFlag[b] = ok;
    }
  }
  __syncthreads();

  if (!s_ok) return;  // fallback path produces the output

  int kc = s_kc;
  float* out5 = out;
  float* ocat = out + BATCH * MAX_OUT * 5;
  for (int r = tid; r < MAX_OUT; r += 1024) {
    float* p = out5 + ((size_t)(b * MAX_OUT + r)) * 5;
    if (r < kc) {
      int i = keptI[r];
      float4 ob = sorg_s[i];
      p[0] = ob.x; p[1] = ob.y; p[2] = ob.z; p[3] = ob.w; p[4] = ssc_s[i];
      ocat[b * MAX_OUT + r] = (float)(slo_s[i] & 0x7Fu);
    } else {
      p[0] = 0.0f; p[1] = 0.0f; p[2] = 0.0f; p[3] = 0.0f; p[4] = 0.0f;
      ocat[b * MAX_OUT + r] = 0.0f;
    }
  }
}

// ======== FALLBACK pipeline (exact 2048 path, gated on !gFlag) =============
__global__ __launch_bounds__(1024) void k_sel2048(const u32* __restrict__ keyhi,
                                                  const u8* __restrict__ cats,
                                                  const float* __restrict__ boxes,
                                                  const u32* __restrict__ gFlag,
                                                  float4* __restrict__ candOff,
                                                  float4* __restrict__ candOrig,
                                                  float* __restrict__ candScore,
                                                  int* __restrict__ candCat) {
  int b = blockIdx.x;
  if (gFlag[b]) return;
  int tid = threadIdx.x;
  int lane = tid & 63;
  __shared__ u32 hist[4096];
  __shared__ u32 sbuf[258];
  __shared__ u64 selk[PRE_K];
  __shared__ u64 ties[128];
  __shared__ u32 s_cnt, s_tcnt;

  const uint4* bh4 = (const uint4*)(keyhi + (size_t)b * NANCH);
  uint4 hk[8];
  #pragma unroll
  for (int j = 0; j < 8; ++j) hk[j] = bh4[tid + j * 1024];

  if (tid == 0) { s_cnt = 0; s_tcnt = 0; }
  for (int i = tid; i < 4096; i += 1024) hist[i] = 0;
  __syncthreads();

#define ELEM(j, c) ((c) == 0 ? hk[j].x : (c) == 1 ? hk[j].y : (c) == 2 ? hk[j].z : hk[j].w)
  #pragma unroll
  for (int j = 0; j < 8; ++j) {
    #pragma unroll
    for (int c = 0; c < 4; ++c) {
      u32 d = ELEM(j, c) >> 24;
      u64 todo = ~0ull;
      while (todo) {
        int src = __ffsll((unsigned long long)todo) - 1;
        u32 dd = __shfl(d, src);
        u64 match = __ballot(d == dd);
        if (lane == src) atomicAdd(&hist[dd], (u32)__popcll(match));
        todo &= ~match;
      }
    }
  }
  __syncthreads();
  int D1, n1;
  scan_digit_fast<256>(hist, PRE_K, sbuf, tid, &D1, &n1);

  for (int i = tid; i < 4096; i += 1024) hist[i] = 0;
  __syncthreads();
  u32 p1 = (u32)D1;
  #pragma unroll
  for (int j = 0; j < 8; ++j) {
    #pragma unroll
    for (int c = 0; c < 4; ++c) {
      u32 h = ELEM(j, c);
      if ((h >> 24) == p1) atomicAdd(&hist[(h >> 12) & 0xFFF], 1u);
    }
  }
  __syncthreads();
  int D2, n2;
  scan_digit_fast<4096>(hist, n1, sbuf, tid, &D2, &n2);

  for (int i = tid; i < 4096; i += 1024) hist[i] = 0;
  __syncthreads();
  u32 p2 = (p1 << 12) | (u32)D2;
  #pragma unroll
  for (int j = 0; j < 8; ++j) {
    #pragma unroll
    for (int c = 0; c < 4; ++c) {
      u32 h = ELEM(j, c);
      if ((h >> 12) == p2) atomicAdd(&hist[h & 0xFFF], 1u);
    }
  }
  __syncthreads();
  int D3, n3;
  scan_digit_fast<4096>(hist, n2, sbuf, tid, &D3, &n3);

  u32 S32 = (p2 << 12) | (u32)D3;
  int need3 = n3;

  #pragma unroll
  for (int j = 0; j < 8; ++j) {
    #pragma unroll
    for (int c = 0; c < 4; ++c) {
      u32 h = ELEM(j, c);
      u32 n = (u32)(4 * tid + 4096 * j + c);
      u64 k = ((u64)h << 32) | (u64)(0xFFFFFFFFu - n);
      bool gt = h > S32;
      u64 m = __ballot(gt);
      u32 wbase = 0;
      if (lane == 0 && m) wbase = atomicAdd(&s_cnt, (u32)__popcll(m));
      wbase = __shfl(wbase, 0);
      if (gt) {
        u32 pos = wbase + (u32)__popcll(m & ((1ull << lane) - 1));
        if (pos < PRE_K) selk[pos] = k;
      }
      if (h == S32) {
        u32 tp = atomicAdd(&s_tcnt, 1u);
        if (tp < 128) ties[tp] = k;
      }
    }
  }
#undef ELEM
  __syncthreads();

  int nt = (int)s_tcnt; if (nt > 128) nt = 128;
  int base = (int)s_cnt;
  if (tid < nt) {
    u64 my = ties[tid];
    int r = 0;
    for (int j = 0; j < nt; ++j) r += (ties[j] > my);
    if (r < need3 && base + r < PRE_K) selk[base + r] = my;
  }
  __syncthreads();

  for (int k = 2; k <= PRE_K; k <<= 1) {
    for (int j = k >> 1; j > 0; j >>= 1) {
      for (int idx = tid; idx < PRE_K; idx += 1024) {
        int ixj = idx ^ j;
        if (ixj > idx) {
          u64 a = selk[idx], c = selk[ixj];
          bool up = ((idx & k) == 0);
          if ((a > c) == up) { selk[idx] = c; selk[ixj] = a; }
        }
      }
      __syncthreads();
    }
  }

  for (int r = tid; r < PRE_K; r += 1024) {
    u64 my = selk[PRE_K - 1 - r];
    u32 n = 0xFFFFFFFFu - (u32)(my & 0xFFFFFFFFu);
    float s = sort2f((u32)(my >> 32));
    int cat = (int)cats[(size_t)b * NANCH + n];
    const float* bp = boxes + ((size_t)b * NANCH + n) * 4;
    float4 ob = make_float4(bp[0], bp[1], bp[2], bp[3]);
    float off = 2.0f * (float)cat;
    float4 obo = make_float4(ob.x + off, ob.y + off, ob.z + off, ob.w + off);
    int o = b * PRE_K + r;
    candOff[o] = obo;
    candOrig[o] = ob;
    candScore[o] = s;
    candCat[o] = cat;
  }
}

__global__ __launch_bounds__(256) void k_mask2048(const float4* __restrict__ candOff,
                                                  const u32* __restrict__ gFlag,
                                                  u64* __restrict__ mask) {
  int b = blockIdx.y;
  if (gFlag[b]) return;
  int tid = threadIdx.x;
  int wave = tid >> 6, lane = tid & 63;
  __shared__ float4 sb[PRE_K];
  __shared__ float sarea[PRE_K];
  for (int j = tid; j < PRE_K; j += 256) {
    float4 v = candOff[b * PRE_K + j];
    sb[j] = v;
    sarea[j] = fmaxf(v.z - v.x, 0.0f) * fmaxf(v.w - v.y, 0.0f);
  }
  __syncthreads();

  int gw = blockIdx.x * 4 + wave;
  for (int k = 0; k < PRE_K / 256; ++k) {
    int i = gw + 256 * k;
    float4 bi = sb[i];
    float ai = sarea[i];
    int c0 = i >> 6;
    u64 myword = 0;
    for (int c = c0; c < 32; ++c) {
      float4 bj = sb[c * 64 + lane];
      float aj = sarea[c * 64 + lane];
      float lx = fmaxf(bi.x, bj.x), ly = fmaxf(bi.y, bj.y);
      float rx = fminf(bi.z, bj.z), ry = fminf(bi.w, bj.w);
      float iw = fmaxf(rx - lx, 0.0f), ih = fmaxf(ry - ly, 0.0f);
      float inter = iw * ih;
      float uni = fmaxf(ai + aj - inter, 1e-9f);
      u64 word = __ballot(inter > 0.5f * uni);
      if (lane == c) myword = word;
    }
    if (lane < 32) mask[((size_t)(b * PRE_K + i)) * 32 + lane] = myword;
  }
}

__global__ __launch_bounds__(64) void k_scan2048(const u64* __restrict__ mask,
                                                 const float4* __restrict__ candOrig,
                                                 const float* __restrict__ candScore,
                                                 const int* __restrict__ candCat,
                                                 const u32* __restrict__ gFlag,
                                                 float* __restrict__ out) {
  int b = blockIdx.x;
  if (gFlag[b]) return;
  int tid = threadIdx.x;
  __shared__ float ssc[PRE_K];
  __shared__ int keptI[MAX_OUT];
  for (int j = tid; j < PRE_K; j += 64) ssc[j] = candScore[b * PRE_K + j];
  __syncthreads();

  const u64* mrow = mask + (size_t)b * PRE_K * 32;
  int wsel = tid & 31;
  bool lo32 = tid < 32;
  u64 remv = 0;
  int cnt = 0;

  u64 c0=0,c1=0,c2=0,c3=0,c4=0,c5=0,c6=0,c7=0;
  if (lo32) {
    c0 = mrow[0 * 32 + wsel]; c1 = mrow[1 * 32 + wsel];
    c2 = mrow[2 * 32 + wsel]; c3 = mrow[3 * 32 + wsel];
    c4 = mrow[4 * 32 + wsel]; c5 = mrow[5 * 32 + wsel];
    c6 = mrow[6 * 32 + wsel]; c7 = mrow[7 * 32 + wsel];
  }

#define PROCESS(I, RK)                                   \
  {                                                      \
    u64 wb = __shfl(remv, (I) >> 6);                     \
    bool sup = (wb >> ((I) & 63)) & 1ull;                \
    if (!sup && ssc[I] > SCORE_TH) {                     \
      if (tid == 0 && cnt < MAX_OUT) keptI[cnt] = (I);   \
      if (lo32) remv |= (RK);                            \
      cnt++;                                             \
    }                                                    \
  }

  for (int base = 0; base < PRE_K; base += 8) {
    u64 n0=0,n1=0,n2=0,n3=0,n4=0,n5=0,n6=0,n7=0;
    if (base + 8 < PRE_K && lo32) {
      const u64* nr = mrow + (size_t)(base + 8) * 32 + wsel;
      n0 = nr[0 * 32]; n1 = nr[1 * 32]; n2 = nr[2 * 32]; n3 = nr[3 * 32];
      n4 = nr[4 * 32]; n5 = nr[5 * 32]; n6 = nr[6 * 32]; n7 = nr[7 * 32];
    }
    PROCESS(base + 0, c0); PROCESS(base + 1, c1);
    PROCESS(base + 2, c2); PROCESS(base + 3, c3);
    PROCESS(base + 4, c4); PROCESS(base + 5, c5);
    PROCESS(base + 6, c6); PROCESS(base + 7, c7);
    c0=n0; c1=n1; c2=n2; c3=n3; c4=n4; c5=n5; c6=n6; c7=n7;
    if (cnt >= MAX_OUT) break;
  }
#undef PROCESS

  int kc = cnt < MAX_OUT ? cnt : MAX_OUT;
  __syncthreads();

  float* out5 = out;
  float* ocat = out + BATCH * MAX_OUT * 5;
  for (int r = tid; r < MAX_OUT; r += 64) {
    float* p = out5 + ((size_t)(b * MAX_OUT + r)) * 5;
    if (r < kc) {
      int i = keptI[r];
      float4 ob = candOrig[b * PRE_K + i];
      p[0] = ob.x; p[1] = ob.y; p[2] = ob.z; p[3] = ob.w; p[4] = ssc[i];
      ocat[b * MAX_OUT + r] = (float)candCat[b * PRE_K + i];
    } else {
      p[0] = 0.0f; p[1] = 0.0f; p[2] = 0.0f; p[3] = 0.0f; p[4] = 0.0f;
      ocat[b * MAX_OUT + r] = 0.0f;
    }
  }
}

extern "C" void kernel_launch(void* const* d_in, const int* in_sizes, int n_in,
                              void* d_out, int out_size, void* d_ws, size_t ws_size,
                              hipStream_t stream) {
  const float* boxes = (const float*)d_in[0];
  const float* confs = (const float*)d_in[1];
  float* out = (float*)d_out;
  char* ws = (char*)d_ws;

  const size_t OFF_KHI  = 0;                            // 1 MB
  const size_t OFF_CATS = (size_t)1 << 20;              // 256 KB
  const size_t OFF_CNT  = OFF_CATS + (256u << 10);      // 4 KB (u8 per block)
  const size_t OFF_FLAG = OFF_CNT + 4096;               // 64 B
  const size_t OFF_CB   = OFF_FLAG + 64;                // 512 KB slotted candidates
  const size_t OFF_COFF = OFF_CB + (size_t)4096 * SLOTS * 8;  // 256 KB (fallback)
  const size_t OFF_CORG = OFF_COFF + (256u << 10);      // 256 KB
  const size_t OFF_CSC  = OFF_CORG + (256u << 10);      // 64 KB
  const size_t OFF_CCAT = OFF_CSC + (64u << 10);        // 64 KB
  const size_t OFF_MASK = OFF_CCAT + (64u << 10);       // 4 MB

  u32* keyhi   = (u32*)(ws + OFF_KHI);
  u8* cats     = (u8*)(ws + OFF_CATS);
  u8* cntA     = (u8*)(ws + OFF_CNT);
  u32* gFlag   = (u32*)(ws + OFF_FLAG);
  u64* candBuf = (u64*)(ws + OFF_CB);
  float4* cOff = (float4*)(ws + OFF_COFF);
  float4* cOrg = (float4*)(ws + OFF_CORG);
  float* cSc   = (float*)(ws + OFF_CSC);
  int* cCat    = (int*)(ws + OFF_CCAT);
  u64* mask    = (u64*)(ws + OFF_MASK);

  k_score<<<BATCH * NANCH / 64, 256, 0, stream>>>(confs, keyhi, cats, candBuf, cntA);
  k_sel<<<BATCH, 1024, 0, stream>>>(candBuf, cntA, boxes, out, gFlag);
  // fallback (exact 2048 path), no-ops when gFlag[b] == 1
  k_sel2048<<<BATCH, 1024, 0, stream>>>(keyhi, cats, boxes, gFlag, cOff, cOrg, cSc, cCat);
  dim3 g3(64, BATCH);
  k_mask2048<<<g3, 256, 0, stream>>>(cOff, gFlag, mask);
  k_scan2048<<<BATCH, 64, 0, stream>>>(mask, cOrg, cSc, cCat, gFlag, out);
}

// Round 18
// 66.393 us; speedup vs baseline: 1.6795x; 1.0528x over previous
//
#include <hip/hip_runtime.h>
#include <stdint.h>

#define BATCH 8
#define NANCH 32768
#define NCLS 81
#define PRE_K 2048
#define PK1 256
#define CAP 1024
#define SLOTS 16
#define MAX_OUT 200
#define SCORE_TH 0.05f
#define T0 0.9998f

typedef uint32_t u32;
typedef uint64_t u64;
typedef uint8_t u8;

__device__ __forceinline__ u32 f2sort(float f) {
  u32 u = __float_as_uint(f);
  return (u & 0x80000000u) ? ~u : (u | 0x80000000u);
}
__device__ __forceinline__ float sort2f(u32 u) {
  u = (u & 0x80000000u) ? (u & 0x7FFFFFFFu) : ~u;
  return __uint_as_float(u);
}
__device__ __forceinline__ u64 shfl_xor64(u64 x, int m) {
  u32 lo = (u32)__shfl_xor((int)(u32)x, m);
  u32 hi = (u32)__shfl_xor((int)(u32)(x >> 32), m);
  return ((u64)hi << 32) | lo;
}

// ---------------- kernel 1: score + ATOMIC-FREE slotted pre-filter ---------
__global__ __launch_bounds__(256) void k_score(const float* __restrict__ confs,
                                               u32* __restrict__ keyhi,
                                               u8* __restrict__ cats,
                                               u64* __restrict__ candBuf,
                                               u8* __restrict__ cntA) {
  __shared__ float st[64 * NCLS];
  __shared__ u32 outh[64];
  __shared__ u8 outc[64];
  int tid = threadIdx.x;
  const float4* src = (const float4*)confs + (size_t)blockIdx.x * (64 * NCLS / 4);
  float4* dst = (float4*)st;
  for (int idx = tid; idx < 64 * NCLS / 4; idx += 256) dst[idx] = src[idx];
  __syncthreads();

  int a = tid >> 2, s = tid & 3;
  const float* row = st + a * NCLS;
  int c0 = s * 20;
  int cnt = (s == 3) ? 21 : 20;
  u64 key = 0;
  for (int k = 0; k < cnt; ++k) {
    int c = c0 + k;
    u64 k2 = ((u64)__float_as_uint(row[c]) << 7) | (u32)(127 - c);
    if (k2 > key) key = k2;
  }
  u64 o = __shfl_xor(key, 1); if (o > key) key = o;
  o = __shfl_xor(key, 2); if (o > key) key = o;
  if (s == 0) {
    float v = __uint_as_float((u32)(key >> 7));
    int c = 127 - (int)(key & 127);
    bool valid = (v > SCORE_TH) && (c != 0);
    float sc = valid ? v : -1.0f;
    outh[a] = f2sort(sc);
    outc[a] = (u8)c;
  }
  __syncthreads();
  if (tid < 64) {
    int g = blockIdx.x * 64 + tid;
    u32 h = outh[tid];
    u8 c = outc[tid];
    keyhi[g] = h;
    cats[g] = c;
    const u32 H0 = f2sort(T0);
    bool q = h > H0;
    u64 qm = __ballot(q);
    if (q) {
      u32 pos = (u32)__popcll(qm & ((1ull << tid) - 1));
      if (pos < SLOTS) {
        u32 n = (u32)(g & (NANCH - 1));
        u64 k = ((u64)h << 32) | ((u64)(0x7FFFu - n) << 7) | (u64)c;
        candBuf[(size_t)blockIdx.x * SLOTS + pos] = k;
      }
    }
    if (tid == 0) {
      u32 cb = (u32)__popcll(qm);
      cntA[blockIdx.x] = (u8)(cb > 255 ? 255 : cb);
    }
  }
}

// -------- wave-scan digit finder ---------
template <int B>
__device__ void scan_digit_fast(const u32* gh, int need, u32* sbuf,
                                int tid, int* D, int* NO) {
  const int CS = B / 256;
  if (tid < 256) {
    int hi = B - 1 - tid * CS;
    u32 s = 0;
    #pragma unroll 4
    for (int k = 0; k < CS; ++k) s += gh[hi - k];
    sbuf[tid] = s;
  }
  __syncthreads();
  if (tid < 64) {
    u32 v0 = sbuf[tid * 4], v1 = sbuf[tid * 4 + 1];
    u32 v2 = sbuf[tid * 4 + 2], v3 = sbuf[tid * 4 + 3];
    u32 loc = v0 + v1 + v2 + v3;
    u32 inc = loc;
    #pragma unroll
    for (int off = 1; off < 64; off <<= 1) {
      u32 ov = __shfl_up(inc, off);
      if (tid >= off) inc += ov;
    }
    u32 exc = inc - loc;
    if (exc < (u32)need && inc >= (u32)need) {
      int acc = (int)exc;
      u32 vs[4] = {v0, v1, v2, v3};
      #pragma unroll
      for (int c = 0; c < 4; ++c) {
        if (acc + (int)vs[c] >= need) {
          int h2 = B - 1 - (tid * 4 + c) * CS;
          for (int k = 0; k < CS; ++k) {
            u32 h = gh[h2 - k];
            acc += (int)h;
            if (acc >= need) {
              sbuf[256] = (u32)(h2 - k);
              sbuf[257] = (u32)(need - (acc - (int)h));
              break;
            }
          }
          break;
        }
        acc += (int)vs[c];
      }
    }
  }
  __syncthreads();
  *D = (int)sbuf[256];
  *NO = (int)sbuf[257];
  __syncthreads();
}

// ======== kernel 2: slot-gather + top-256 + reg-sort + mask + scan + out ===
__global__ __launch_bounds__(1024) void k_sel(const u64* __restrict__ candBuf,
                                              const u8* __restrict__ cntA,
                                              const float* __restrict__ boxes,
                                              float* __restrict__ out,
                                              u32* __restrict__ gFlag) {
  int b = blockIdx.x;
  int tid = threadIdx.x;
  int lane = tid & 63;
  int wid = tid >> 6;
  __shared__ u32 hist[4096];
  __shared__ u32 sbuf[258];
  __shared__ u64 cand[CAP];
  __shared__ u64 selk[PK1];
  __shared__ u64 ties[128];
  __shared__ u32 wtot[8], woff[8];
  __shared__ u32 s_cnt, s_tcnt, s_tot, s_bad;
  __shared__ int s_kc;
  __shared__ u32 s_ok;
  __shared__ u32 slo_s[PK1];
  __shared__ float ssc_s[PK1];
  __shared__ float4 sbo_s[PK1];
  __shared__ float4 sorg_s[PK1];
  __shared__ float sar_s[PK1];
  __shared__ u64 mk[PK1][4];
  __shared__ int keptI[MAX_OUT];

  if (tid == 0) { s_cnt = 0; s_tcnt = 0; s_bad = 0; }
  for (int i = tid; i < 4096; i += 1024) hist[i] = 0;
  __syncthreads();

  // ---- gather candidates from per-block slots -----------------------------
  u32 c = 0;
  if (tid < 512) {
    c = (u32)cntA[b * 512 + tid];
    if (c > SLOTS) atomicOr(&s_bad, 1u);
  }
  u32 inc = c;
  #pragma unroll
  for (int off = 1; off < 64; off <<= 1) {
    u32 ov = __shfl_up(inc, off);
    if (lane >= off) inc += ov;
  }
  if (tid < 512 && lane == 63) wtot[wid] = inc;
  __syncthreads();
  if (tid == 0) {
    u32 acc = 0;
    #pragma unroll
    for (int i = 0; i < 8; ++i) { woff[i] = acc; acc += wtot[i]; }
    s_tot = acc;
  }
  __syncthreads();
  if (tid < 512 && c) {
    u32 exc = inc - c + woff[wid];
    u32 cc = c > SLOTS ? SLOTS : c;
    const u64* sp = candBuf + (size_t)(b * 512 + tid) * SLOTS;
    for (u32 k = 0; k < cc; ++k) {
      u32 p = exc + k;
      if (p < CAP) cand[p] = sp[k];
    }
  }
  __syncthreads();

  u32 tot = s_tot;
  if (s_bad || tot < PK1 || tot > CAP) {
    if (tid == 0) gFlag[b] = 0;
    return;
  }

  // ---- 12-bit mid-digit hist ---------------------------------------------
  u64 myk = (tid < (int)tot) ? cand[tid] : 0;
  u32 dig = (u32)(myk >> 40) & 0xFFF;
  if (tid < (int)tot) atomicAdd(&hist[dig], 1u);
  __syncthreads();
  int D1, n1;
  scan_digit_fast<4096>(hist, PK1, sbuf, tid, &D1, &n1);
  int need = n1;

  // ---- compaction ---------------------------------------------------------
  {
    bool gt = (tid < (int)tot) && ((int)dig > D1);
    u64 m = __ballot(gt);
    u32 wbase = 0;
    if (lane == 0 && m) wbase = atomicAdd(&s_cnt, (u32)__popcll(m));
    wbase = __shfl(wbase, 0);
    if (gt) {
      u32 pos = wbase + (u32)__popcll(m & ((1ull << lane) - 1));
      if (pos < PK1) selk[pos] = myk;
    }
    bool te = (tid < (int)tot) && ((int)dig == D1);
    if (te) {
      u32 tp = atomicAdd(&s_tcnt, 1u);
      if (tp < 128) ties[tp] = myk;
    }
  }
  __syncthreads();

  bool tieOK = (s_tcnt <= 128u);
  {
    int nt = (int)s_tcnt; if (nt > 128) nt = 128;
    int base = (int)s_cnt;
    if (tid < nt) {
      u64 my = ties[tid];
      int r = 0;
      for (int j = 0; j < nt; ++j) r += (ties[j] > my);
      if (r < need && base + r < PK1) selk[base + r] = my;
    }
  }
  __syncthreads();

  // ---- in-register bitonic sort of 256 keys in wave 0 ---------------------
  if (tid < 64) {
    u64 v0 = selk[lane], v1 = selk[64 + lane], v2 = selk[128 + lane], v3 = selk[192 + lane];

#define CAS_REG(A, B, UP) { u64 ta = A, tb = B; if ((ta > tb) == (UP)) { A = tb; B = ta; } }
#define CAS_SHF(R, J, UP) { u64 o = shfl_xor64(R, (J)); bool tm = (((lane & (J)) == 0) == (UP)); \
                            u64 mn = (o < R) ? o : R; u64 mx = (o < R) ? R : o; R = tm ? mn : mx; }
    #pragma unroll
    for (int k = 2; k <= 32; k <<= 1) {
      #pragma unroll
      for (int j = k >> 1; j > 0; j >>= 1) {
        bool u0 = (lane & k) == 0;
        CAS_SHF(v0, j, u0) CAS_SHF(v1, j, u0) CAS_SHF(v2, j, u0) CAS_SHF(v3, j, u0)
      }
    }
    #pragma unroll
    for (int j = 32; j > 0; j >>= 1) {
      CAS_SHF(v0, j, true) CAS_SHF(v1, j, false) CAS_SHF(v2, j, true) CAS_SHF(v3, j, false)
    }
    CAS_REG(v0, v1, true) CAS_REG(v2, v3, false)
    #pragma unroll
    for (int j = 32; j > 0; j >>= 1) {
      CAS_SHF(v0, j, true) CAS_SHF(v1, j, true) CAS_SHF(v2, j, false) CAS_SHF(v3, j, false)
    }
    CAS_REG(v0, v2, true) CAS_REG(v1, v3, true)
    CAS_REG(v0, v1, true) CAS_REG(v2, v3, true)
    #pragma unroll
    for (int j = 32; j > 0; j >>= 1) {
      CAS_SHF(v0, j, true) CAS_SHF(v1, j, true) CAS_SHF(v2, j, true) CAS_SHF(v3, j, true)
    }
#undef CAS_REG
#undef CAS_SHF

    #pragma unroll
    for (int r = 0; r < 4; ++r) {
      u64 key = (r == 0) ? v0 : (r == 1) ? v1 : (r == 2) ? v2 : v3;
      int d = 255 - (r * 64 + lane);
      slo_s[d] = (u32)key;
      ssc_s[d] = sort2f((u32)(key >> 32));
    }
  }
  __syncthreads();

  // ---- gather boxes in sorted order ---------------------------------------
  if (tid < PK1) {
    u32 lo = slo_s[tid];
    u32 n = 0x7FFFu - ((lo >> 7) & 0x7FFFu);
    int cat = (int)(lo & 0x7Fu);
    const float* bp = boxes + ((size_t)b * NANCH + n) * 4;
    float4 ob = make_float4(bp[0], bp[1], bp[2], bp[3]);
    float off = 2.0f * (float)cat;
    float4 obo = make_float4(ob.x + off, ob.y + off, ob.z + off, ob.w + off);
    sorg_s[tid] = ob;
    sbo_s[tid] = obo;
    sar_s[tid] = fmaxf(obo.z - obo.x, 0.0f) * fmaxf(obo.w - obo.y, 0.0f);
  }
  __syncthreads();

  // ---- 256x256 mask, column-swizzled --------------------------------------
  {
    int i = tid >> 2, w = tid & 3;
    float4 bi = sbo_s[i];
    float ai = sar_s[i];
    u64 word = 0;
    int j0 = w * 64, wsw = w << 1;
    for (int jj = 0; jj < 64; ++jj) {
      int jp = jj ^ wsw;
      float4 bj = sbo_s[j0 + jp];
      float lx = fmaxf(bi.x, bj.x), ly = fmaxf(bi.y, bj.y);
      float rx = fminf(bi.z, bj.z), ry = fminf(bi.w, bj.w);
      float iw = fmaxf(rx - lx, 0.0f), ih = fmaxf(ry - ly, 0.0f);
      float inter = iw * ih;
      float uni = fmaxf(ai + sar_s[j0 + jp] - inter, 1e-9f);
      if (inter > 0.5f * uni) word |= (1ull << jp);
    }
    mk[i][w] = word;
  }
  __syncthreads();

  // ---- greedy scan, wave 0, 8-deep register prefetch ----------------------
  if (tid < 64) {
    bool l4 = lane < 4;
    u64 remv = 0;
    int kcnt = 0;
    u64 m0=0,m1=0,m2=0,m3=0,m4=0,m5=0,m6=0,m7=0;
    float s0, s1, s2, s3, s4, s5, s6, s7;
    if (l4) {
      m0 = mk[0][lane]; m1 = mk[1][lane]; m2 = mk[2][lane]; m3 = mk[3][lane];
      m4 = mk[4][lane]; m5 = mk[5][lane]; m6 = mk[6][lane]; m7 = mk[7][lane];
    }
    s0 = ssc_s[0]; s1 = ssc_s[1]; s2 = ssc_s[2]; s3 = ssc_s[3];
    s4 = ssc_s[4]; s5 = ssc_s[5]; s6 = ssc_s[6]; s7 = ssc_s[7];

#define PROC(D)                                                       \
    {                                                                 \
      int i = base8 + (D);                                            \
      u64 wb = __shfl(remv, i >> 6);                                  \
      bool sup = (wb >> (i & 63)) & 1ull;                             \
      if (!sup && s##D > SCORE_TH) {                                  \
        if (lane == 0 && kcnt < MAX_OUT) keptI[kcnt] = i;             \
        if (l4) remv |= m##D;                                         \
        kcnt++;                                                       \
      }                                                               \
    }

    for (int base8 = 0; base8 < PK1; base8 += 8) {
      u64 t0=0,t1=0,t2=0,t3=0,t4=0,t5=0,t6=0,t7=0;
      float u0=0,u1=0,u2=0,u3=0,u4=0,u5=0,u6=0,u7=0;
      if (base8 + 8 < PK1) {
        int nb = base8 + 8;
        if (l4) {
          t0 = mk[nb+0][lane]; t1 = mk[nb+1][lane]; t2 = mk[nb+2][lane]; t3 = mk[nb+3][lane];
          t4 = mk[nb+4][lane]; t5 = mk[nb+5][lane]; t6 = mk[nb+6][lane]; t7 = mk[nb+7][lane];
        }
        u0 = ssc_s[nb+0]; u1 = ssc_s[nb+1]; u2 = ssc_s[nb+2]; u3 = ssc_s[nb+3];
        u4 = ssc_s[nb+4]; u5 = ssc_s[nb+5]; u6 = ssc_s[nb+6]; u7 = ssc_s[nb+7];
      }
      PROC(0) PROC(1) PROC(2) PROC(3) PROC(4) PROC(5) PROC(6) PROC(7)
      m0=t0; m1=t1; m2=t2; m3=t3; m4=t4; m5=t5; m6=t6; m7=t7;
      s0=u0; s1=u1; s2=u2; s3=u3; s4=u4; s5=u5; s6=u6; s7=u7;
      if (kcnt >= MAX_OUT) break;
    }
#undef PROC

    if (lane == 0) {
      s_kc = kcnt < MAX_OUT ? kcnt : MAX_OUT;
      u32 ok = (kcnt >= MAX_OUT) && tieOK;
      s_ok = ok;
      gFlag[b] = ok;
    }
  }
  __syncthreads();

  if (!s_ok) return;

  int kc = s_kc;
  float* out5 = out;
  float* ocat = out + BATCH * MAX_OUT * 5;
  for (int r = tid; r < MAX_OUT; r += 1024) {
    float* p = out5 + ((size_t)(b * MAX_OUT + r)) * 5;
    if (r < kc) {
      int i = keptI[r];
      float4 ob = sorg_s[i];
      p[0] = ob.x; p[1] = ob.y; p[2] = ob.z; p[3] = ob.w; p[4] = ssc_s[i];
      ocat[b * MAX_OUT + r] = (float)(slo_s[i] & 0x7Fu);
    } else {
      p[0] = 0.0f; p[1] = 0.0f; p[2] = 0.0f; p[3] = 0.0f; p[4] = 0.0f;
      ocat[b * MAX_OUT + r] = 0.0f;
    }
  }
}

// ======== kernel 3: FUSED exact-2048 fallback (gated; never fires here) ====
// Phases separated by threadfence+syncthreads; global cand/mask round-trips.
__global__ __launch_bounds__(1024) void k_fallback(const u32* __restrict__ keyhi,
                                                   const u8* __restrict__ cats,
                                                   const float* __restrict__ boxes,
                                                   const u32* __restrict__ gFlag,
                                                   float4* __restrict__ candOff,
                                                   float4* __restrict__ candOrig,
                                                   float* __restrict__ candScore,
                                                   int* __restrict__ candCat,
                                                   u64* __restrict__ mask,
                                                   float* __restrict__ out) {
  int b = blockIdx.x;
  if (gFlag[b]) return;
  int tid = threadIdx.x;
  int lane = tid & 63;

  __shared__ u32 hist[4096];
  __shared__ u32 sbuf[258];
  __shared__ u64 selk[PRE_K];     // 16 KB
  __shared__ u64 ties[128];
  __shared__ u32 s_cnt, s_tcnt;
  __shared__ int keptI[MAX_OUT];

  const uint4* bh4 = (const uint4*)(keyhi + (size_t)b * NANCH);
  uint4 hk[8];
  #pragma unroll
  for (int j = 0; j < 8; ++j) hk[j] = bh4[tid + j * 1024];

  if (tid == 0) { s_cnt = 0; s_tcnt = 0; }
  for (int i = tid; i < 4096; i += 1024) hist[i] = 0;
  __syncthreads();

#define ELEM(j, c) ((c) == 0 ? hk[j].x : (c) == 1 ? hk[j].y : (c) == 2 ? hk[j].z : hk[j].w)
  #pragma unroll
  for (int j = 0; j < 8; ++j) {
    #pragma unroll
    for (int c = 0; c < 4; ++c) {
      u32 d = ELEM(j, c) >> 24;
      u64 todo = ~0ull;
      while (todo) {
        int src = __ffsll((unsigned long long)todo) - 1;
        u32 dd = __shfl(d, src);
        u64 match = __ballot(d == dd);
        if (lane == src) atomicAdd(&hist[dd], (u32)__popcll(match));
        todo &= ~match;
      }
    }
  }
  __syncthreads();
  int D1, n1;
  scan_digit_fast<256>(hist, PRE_K, sbuf, tid, &D1, &n1);

  for (int i = tid; i < 4096; i += 1024) hist[i] = 0;
  __syncthreads();
  u32 p1 = (u32)D1;
  #pragma unroll
  for (int j = 0; j < 8; ++j) {
    #pragma unroll
    for (int c = 0; c < 4; ++c) {
      u32 h = ELEM(j, c);
      if ((h >> 24) == p1) atomicAdd(&hist[(h >> 12) & 0xFFF], 1u);
    }
  }
  __syncthreads();
  int D2, n2;
  scan_digit_fast<4096>(hist, n1, sbuf, tid, &D2, &n2);

  for (int i = tid; i < 4096; i += 1024) hist[i] = 0;
  __syncthreads();
  u32 p2 = (p1 << 12) | (u32)D2;
  #pragma unroll
  for (int j = 0; j < 8; ++j) {
    #pragma unroll
    for (int c = 0; c < 4; ++c) {
      u32 h = ELEM(j, c);
      if ((h >> 12) == p2) atomicAdd(&hist[h & 0xFFF], 1u);
    }
  }
  __syncthreads();
  int D3, n3;
  scan_digit_fast<4096>(hist, n2, sbuf, tid, &D3, &n3);

  u32 S32 = (p2 << 12) | (u32)D3;
  int need3 = n3;

  #pragma unroll
  for (int j = 0; j < 8; ++j) {
    #pragma unroll
    for (int c = 0; c < 4; ++c) {
      u32 h = ELEM(j, c);
      u32 n = (u32)(4 * tid + 4096 * j + c);
      u64 k = ((u64)h << 32) | (u64)(0xFFFFFFFFu - n);
      bool gt = h > S32;
      u64 m = __ballot(gt);
      u32 wbase = 0;
      if (lane == 0 && m) wbase = atomicAdd(&s_cnt, (u32)__popcll(m));
      wbase = __shfl(wbase, 0);
      if (gt) {
        u32 pos = wbase + (u32)__popcll(m & ((1ull << lane) - 1));
        if (pos < PRE_K) selk[pos] = k;
      }
      if (h == S32) {
        u32 tp = atomicAdd(&s_tcnt, 1u);
        if (tp < 128) ties[tp] = k;
      }
    }
  }
#undef ELEM
  __syncthreads();

  {
    int nt = (int)s_tcnt; if (nt > 128) nt = 128;
    int base = (int)s_cnt;
    if (tid < nt) {
      u64 my = ties[tid];
      int r = 0;
      for (int j = 0; j < nt; ++j) r += (ties[j] > my);
      if (r < need3 && base + r < PRE_K) selk[base + r] = my;
    }
  }
  __syncthreads();

  for (int k = 2; k <= PRE_K; k <<= 1) {
    for (int j = k >> 1; j > 0; j >>= 1) {
      for (int idx = tid; idx < PRE_K; idx += 1024) {
        int ixj = idx ^ j;
        if (ixj > idx) {
          u64 a = selk[idx], c = selk[ixj];
          bool up = ((idx & k) == 0);
          if ((a > c) == up) { selk[idx] = c; selk[ixj] = a; }
        }
      }
      __syncthreads();
    }
  }

  // emit candidate records to global
  for (int r = tid; r < PRE_K; r += 1024) {
    u64 my = selk[PRE_K - 1 - r];
    u32 n = 0xFFFFFFFFu - (u32)(my & 0xFFFFFFFFu);
    float s = sort2f((u32)(my >> 32));
    int cat = (int)cats[(size_t)b * NANCH + n];
    const float* bp = boxes + ((size_t)b * NANCH + n) * 4;
    float4 ob = make_float4(bp[0], bp[1], bp[2], bp[3]);
    float off = 2.0f * (float)cat;
    float4 obo = make_float4(ob.x + off, ob.y + off, ob.z + off, ob.w + off);
    int o = b * PRE_K + r;
    candOff[o] = obo;
    candOrig[o] = ob;
    candScore[o] = s;
    candCat[o] = cat;
  }
  __threadfence();
  __syncthreads();

  // ---- phase B: 2048x2048 upper-triangle mask -> global -------------------
  // reuse hist+selk LDS as box/area staging
  {
    float4* sb = (float4*)selk;          // needs 32 KB: selk(16K)+hist(16K)
    float* sarea = (float*)hist;         // overlap-safe: sb uses selk+hist? no.
    // Stage boxes in two halves to stay within selk's 16 KB: process rows
    // against column halves of 1024 boxes each.
    for (int half = 0; half < 2; ++half) {
      // stage 1024 offset boxes + areas (16 KB + 4 KB)
      for (int j = tid; j < 1024; j += 1024) {
        float4 v = candOff[b * PRE_K + half * 1024 + j];
        sb[j] = v;
        sarea[j] = fmaxf(v.z - v.x, 0.0f) * fmaxf(v.w - v.y, 0.0f);
      }
      __syncthreads();
      // rows: 64 iterations x (32 rows x 32 lanes-as-16-words...) simple map:
      // thread t -> row i = it*32 + (t>>5), word w16 = t&31 covers cols of
      // this half: half*1024 + w16*32.. hmm use 64-bit words: w = t&31 maps to
      // global word (half*16 + (t&15)); use 2 passes of 16 words.
      for (int it = 0; it < 64; ++it) {
        int i = it * 32 + (tid >> 5);
        int wl = tid & 31;            // 0..31: word-in-half (each 64 cols? no)
        // each half has 1024 cols = 16 u64 words; lanes 16..31 idle pass 2
        if (wl < 16) {
          int gw = half * 16 + wl;    // global word index 0..31
          float4 bi = candOff[b * PRE_K + i];
          float ai = fmaxf(bi.z - bi.x, 0.0f) * fmaxf(bi.w - bi.y, 0.0f);
          u64 word = 0;
          if (gw >= (i >> 6)) {       // upper-triangle words only
            int j0 = wl * 64;
            for (int jj = 0; jj < 64; ++jj) {
              float4 bj = sb[j0 + jj];
              float lx = fmaxf(bi.x, bj.x), ly = fmaxf(bi.y, bj.y);
              float rx = fminf(bi.z, bj.z), ry = fminf(bi.w, bj.w);
              float iw = fmaxf(rx - lx, 0.0f), ih = fmaxf(ry - ly, 0.0f);
              float inter = iw * ih;
              float uni = fmaxf(ai + sarea[j0 + jj] - inter, 1e-9f);
              if (inter > 0.5f * uni) word |= (1ull << jj);
            }
          }
          mask[((size_t)(b * PRE_K + i)) * 32 + gw] = word;
        }
      }
      __syncthreads();
    }
  }
  __threadfence();
  __syncthreads();

  // ---- phase C: greedy scan (wave 0) + output -----------------------------
  {
    float* ssc = (float*)hist;  // 8 KB scores
    for (int j = tid; j < PRE_K; j += 1024) ssc[j] = candScore[b * PRE_K + j];
    __syncthreads();

    if (tid < 64) {
      const u64* mrow = mask + (size_t)b * PRE_K * 32;
      int wsel = lane & 31;
      bool lo32 = lane < 32;
      u64 remv = 0;
      int cnt = 0;
      u64 rowCur = lo32 ? mrow[wsel] : 0;
      for (int i = 0; i < PRE_K && cnt < MAX_OUT; ++i) {
        u64 rowNxt = (i + 1 < PRE_K && lo32) ? mrow[(size_t)(i + 1) * 32 + wsel] : 0ull;
        u64 wb = __shfl(remv, i >> 6);
        bool sup = (wb >> (i & 63)) & 1ull;
        if (!sup && ssc[i] > SCORE_TH) {
          if (lane == 0) keptI[cnt] = i;
          if (lo32) remv |= rowCur;
          cnt++;
        }
        rowCur = rowNxt;
      }
      if (lane == 0) sbuf[0] = (u32)(cnt < MAX_OUT ? cnt : MAX_OUT);
    }
    __syncthreads();

    int kc = (int)sbuf[0];
    float* out5 = out;
    float* ocat = out + BATCH * MAX_OUT * 5;
    for (int r = tid; r < MAX_OUT; r += 1024) {
      float* p = out5 + ((size_t)(b * MAX_OUT + r)) * 5;
      if (r < kc) {
        int i = keptI[r];
        float4 ob = candOrig[b * PRE_K + i];
        p[0] = ob.x; p[1] = ob.y; p[2] = ob.z; p[3] = ob.w; p[4] = ssc[i];
        ocat[b * MAX_OUT + r] = (float)candCat[b * PRE_K + i];
      } else {
        p[0] = 0.0f; p[1] = 0.0f; p[2] = 0.0f; p[3] = 0.0f; p[4] = 0.0f;
        ocat[b * MAX_OUT + r] = 0.0f;
      }
    }
  }
}

extern "C" void kernel_launch(void* const* d_in, const int* in_sizes, int n_in,
                              void* d_out, int out_size, void* d_ws, size_t ws_size,
                              hipStream_t stream) {
  const float* boxes = (const float*)d_in[0];
  const float* confs = (const float*)d_in[1];
  float* out = (float*)d_out;
  char* ws = (char*)d_ws;

  const size_t OFF_KHI  = 0;                            // 1 MB
  const size_t OFF_CATS = (size_t)1 << 20;              // 256 KB
  const size_t OFF_CNT  = OFF_CATS + (256u << 10);      // 4 KB
  const size_t OFF_FLAG = OFF_CNT + 4096;               // 64 B
  const size_t OFF_CB   = OFF_FLAG + 64;                // 512 KB
  const size_t OFF_COFF = OFF_CB + (size_t)4096 * SLOTS * 8;
  const size_t OFF_CORG = OFF_COFF + (256u << 10);
  const size_t OFF_CSC  = OFF_CORG + (256u << 10);
  const size_t OFF_CCAT = OFF_CSC + (64u << 10);
  const size_t OFF_MASK = OFF_CCAT + (64u << 10);       // 4 MB

  u32* keyhi   = (u32*)(ws + OFF_KHI);
  u8* cats     = (u8*)(ws + OFF_CATS);
  u8* cntA     = (u8*)(ws + OFF_CNT);
  u32* gFlag   = (u32*)(ws + OFF_FLAG);
  u64* candBuf = (u64*)(ws + OFF_CB);
  float4* cOff = (float4*)(ws + OFF_COFF);
  float4* cOrg = (float4*)(ws + OFF_CORG);
  float* cSc   = (float*)(ws + OFF_CSC);
  int* cCat    = (int*)(ws + OFF_CCAT);
  u64* mask    = (u64*)(ws + OFF_MASK);

  k_score<<<BATCH * NANCH / 64, 256, 0, stream>>>(confs, keyhi, cats, candBuf, cntA);
  k_sel<<<BATCH, 1024, 0, stream>>>(candBuf, cntA, boxes, out, gFlag);
  k_fallback<<<BATCH, 1024, 0, stream>>>(keyhi, cats, boxes, gFlag,
                                         cOff, cOrg, cSc, cCat, mask, out);
}

// Round 19
// 64.216 us; speedup vs baseline: 1.7365x; 1.0339x over previous
//
#include <hip/hip_runtime.h>
#include <stdint.h>

#define BATCH 8
#define NANCH 32768
#define NCLS 81
#define PRE_K 2048
#define PK1 256
#define CAP 1024
#define SLOTS 16
#define MAX_OUT 200
#define SCORE_TH 0.05f
#define T0 0.9998f

typedef uint32_t u32;
typedef uint64_t u64;
typedef uint8_t u8;

__device__ __forceinline__ u32 f2sort(float f) {
  u32 u = __float_as_uint(f);
  return (u & 0x80000000u) ? ~u : (u | 0x80000000u);
}
__device__ __forceinline__ float sort2f(u32 u) {
  u = (u & 0x80000000u) ? (u & 0x7FFFFFFFu) : ~u;
  return __uint_as_float(u);
}
__device__ __forceinline__ u64 shfl_xor64(u64 x, int m) {
  u32 lo = (u32)__shfl_xor((int)(u32)x, m);
  u32 hi = (u32)__shfl_xor((int)(u32)(x >> 32), m);
  return ((u64)hi << 32) | lo;
}

// ---------------- kernel 1: score + ATOMIC-FREE slotted pre-filter ---------
__global__ __launch_bounds__(256) void k_score(const float* __restrict__ confs,
                                               u32* __restrict__ keyhi,
                                               u8* __restrict__ cats,
                                               u64* __restrict__ candBuf,
                                               u8* __restrict__ cntA) {
  __shared__ float st[64 * NCLS];
  __shared__ u32 outh[64];
  __shared__ u8 outc[64];
  int tid = threadIdx.x;
  const float4* src = (const float4*)confs + (size_t)blockIdx.x * (64 * NCLS / 4);
  float4* dst = (float4*)st;
  for (int idx = tid; idx < 64 * NCLS / 4; idx += 256) dst[idx] = src[idx];
  __syncthreads();

  int a = tid >> 2, s = tid & 3;
  const float* row = st + a * NCLS;
  int c0 = s * 20;
  int cnt = (s == 3) ? 21 : 20;
  u64 key = 0;
  for (int k = 0; k < cnt; ++k) {
    int c = c0 + k;
    u64 k2 = ((u64)__float_as_uint(row[c]) << 7) | (u32)(127 - c);
    if (k2 > key) key = k2;
  }
  u64 o = __shfl_xor(key, 1); if (o > key) key = o;
  o = __shfl_xor(key, 2); if (o > key) key = o;
  if (s == 0) {
    float v = __uint_as_float((u32)(key >> 7));
    int c = 127 - (int)(key & 127);
    bool valid = (v > SCORE_TH) && (c != 0);
    float sc = valid ? v : -1.0f;
    outh[a] = f2sort(sc);
    outc[a] = (u8)c;
  }
  __syncthreads();
  if (tid < 64) {
    int g = blockIdx.x * 64 + tid;
    u32 h = outh[tid];
    u8 c = outc[tid];
    keyhi[g] = h;
    cats[g] = c;
    const u32 H0 = f2sort(T0);
    bool q = h > H0;
    u64 qm = __ballot(q);
    if (q) {
      u32 pos = (u32)__popcll(qm & ((1ull << tid) - 1));
      if (pos < SLOTS) {
        u32 n = (u32)(g & (NANCH - 1));
        u64 k = ((u64)h << 32) | ((u64)(0x7FFFu - n) << 7) | (u64)c;
        candBuf[(size_t)blockIdx.x * SLOTS + pos] = k;
      }
    }
    if (tid == 0) {
      u32 cb = (u32)__popcll(qm);
      cntA[blockIdx.x] = (u8)(cb > 255 ? 255 : cb);
    }
  }
}

// -------- wave-scan digit finder ---------
template <int B>
__device__ void scan_digit_fast(const u32* gh, int need, u32* sbuf,
                                int tid, int* D, int* NO) {
  const int CS = B / 256;
  if (tid < 256) {
    int hi = B - 1 - tid * CS;
    u32 s = 0;
    #pragma unroll 4
    for (int k = 0; k < CS; ++k) s += gh[hi - k];
    sbuf[tid] = s;
  }
  __syncthreads();
  if (tid < 64) {
    u32 v0 = sbuf[tid * 4], v1 = sbuf[tid * 4 + 1];
    u32 v2 = sbuf[tid * 4 + 2], v3 = sbuf[tid * 4 + 3];
    u32 loc = v0 + v1 + v2 + v3;
    u32 inc = loc;
    #pragma unroll
    for (int off = 1; off < 64; off <<= 1) {
      u32 ov = __shfl_up(inc, off);
      if (tid >= off) inc += ov;
    }
    u32 exc = inc - loc;
    if (exc < (u32)need && inc >= (u32)need) {
      int acc = (int)exc;
      u32 vs[4] = {v0, v1, v2, v3};
      #pragma unroll
      for (int c = 0; c < 4; ++c) {
        if (acc + (int)vs[c] >= need) {
          int h2 = B - 1 - (tid * 4 + c) * CS;
          for (int k = 0; k < CS; ++k) {
            u32 h = gh[h2 - k];
            acc += (int)h;
            if (acc >= need) {
              sbuf[256] = (u32)(h2 - k);
              sbuf[257] = (u32)(need - (acc - (int)h));
              break;
            }
          }
          break;
        }
        acc += (int)vs[c];
      }
    }
  }
  __syncthreads();
  *D = (int)sbuf[256];
  *NO = (int)sbuf[257];
  __syncthreads();
}

// ======== kernel 2: fast NMS path + INLINE gated exact-2048 fallback =======
__global__ __launch_bounds__(1024) void k_sel(const u64* __restrict__ candBuf,
                                              const u8* __restrict__ cntA,
                                              const u32* __restrict__ keyhi,
                                              const u8* __restrict__ cats,
                                              const float* __restrict__ boxes,
                                              float4* __restrict__ candOff,
                                              float4* __restrict__ candOrig,
                                              float* __restrict__ candScore,
                                              int* __restrict__ candCat,
                                              u64* __restrict__ mask,
                                              float* __restrict__ out) {
  int b = blockIdx.x;
  int tid = threadIdx.x;
  int lane = tid & 63;
  int wid = tid >> 6;

  __shared__ u32 hist[4096];     // 16 KB (reused across phases)
  __shared__ u32 sbuf[258];
  __shared__ union {
    struct { u64 cand[CAP]; u64 mk[PK1][4]; } f;  // fast: 8 KB + 8 KB
    u64 selk2[PRE_K];                             // fallback: 16 KB
  } ovl;
  __shared__ u64 selk[PK1];
  __shared__ u64 ties[128];
  __shared__ u32 wtot[8], woff[8];
  __shared__ u32 s_cnt, s_tcnt, s_tot, s_bad;
  __shared__ int s_kc;
  __shared__ u32 s_ok;
  __shared__ u32 slo_s[PK1];
  __shared__ float ssc_s[PK1];
  __shared__ float4 sbo_s[PK1];
  __shared__ float4 sorg_s[PK1];
  __shared__ float sar_s[PK1];
  __shared__ int keptI[MAX_OUT];

  if (tid == 0) { s_cnt = 0; s_tcnt = 0; s_bad = 0; s_ok = 0; }
  for (int i = tid; i < 4096; i += 1024) hist[i] = 0;
  __syncthreads();

  // ---- gather candidates from per-block slots -----------------------------
  u32 c = 0;
  if (tid < 512) {
    c = (u32)cntA[b * 512 + tid];
    if (c > SLOTS) atomicOr(&s_bad, 1u);
  }
  u32 inc = c;
  #pragma unroll
  for (int off = 1; off < 64; off <<= 1) {
    u32 ov = __shfl_up(inc, off);
    if (lane >= off) inc += ov;
  }
  if (tid < 512 && lane == 63) wtot[wid] = inc;
  __syncthreads();
  if (tid == 0) {
    u32 acc = 0;
    #pragma unroll
    for (int i = 0; i < 8; ++i) { woff[i] = acc; acc += wtot[i]; }
    s_tot = acc;
  }
  __syncthreads();
  if (tid < 512 && c) {
    u32 exc = inc - c + woff[wid];
    u32 cc = c > SLOTS ? SLOTS : c;
    const u64* sp = candBuf + (size_t)(b * 512 + tid) * SLOTS;
    for (u32 k = 0; k < cc; ++k) {
      u32 p = exc + k;
      if (p < CAP) ovl.f.cand[p] = sp[k];
    }
  }
  __syncthreads();

  u32 tot = s_tot;
  bool fastOK = !(s_bad || tot < PK1 || tot > CAP);

  if (fastOK) {
    // ---- 12-bit mid-digit hist ---------------------------------------------
    u64 myk = (tid < (int)tot) ? ovl.f.cand[tid] : 0;
    u32 dig = (u32)(myk >> 40) & 0xFFF;
    if (tid < (int)tot) atomicAdd(&hist[dig], 1u);
    __syncthreads();
    int D1, n1;
    scan_digit_fast<4096>(hist, PK1, sbuf, tid, &D1, &n1);
    int need = n1;

    // ---- compaction ---------------------------------------------------------
    {
      bool gt = (tid < (int)tot) && ((int)dig > D1);
      u64 m = __ballot(gt);
      u32 wbase = 0;
      if (lane == 0 && m) wbase = atomicAdd(&s_cnt, (u32)__popcll(m));
      wbase = __shfl(wbase, 0);
      if (gt) {
        u32 pos = wbase + (u32)__popcll(m & ((1ull << lane) - 1));
        if (pos < PK1) selk[pos] = myk;
      }
      bool te = (tid < (int)tot) && ((int)dig == D1);
      if (te) {
        u32 tp = atomicAdd(&s_tcnt, 1u);
        if (tp < 128) ties[tp] = myk;
      }
    }
    __syncthreads();

    bool tieOK = (s_tcnt <= 128u);
    {
      int nt = (int)s_tcnt; if (nt > 128) nt = 128;
      int base = (int)s_cnt;
      if (tid < nt) {
        u64 my = ties[tid];
        int r = 0;
        for (int j = 0; j < nt; ++j) r += (ties[j] > my);
        if (r < need && base + r < PK1) selk[base + r] = my;
      }
    }
    __syncthreads();

    // ---- in-register bitonic sort of 256 keys in wave 0 ---------------------
    if (tid < 64) {
      u64 v0 = selk[lane], v1 = selk[64 + lane], v2 = selk[128 + lane], v3 = selk[192 + lane];

#define CAS_REG(A, B, UP) { u64 ta = A, tb = B; if ((ta > tb) == (UP)) { A = tb; B = ta; } }
#define CAS_SHF(R, J, UP) { u64 o = shfl_xor64(R, (J)); bool tm = (((lane & (J)) == 0) == (UP)); \
                            u64 mn = (o < R) ? o : R; u64 mx = (o < R) ? R : o; R = tm ? mn : mx; }
      #pragma unroll
      for (int k = 2; k <= 32; k <<= 1) {
        #pragma unroll
        for (int j = k >> 1; j > 0; j >>= 1) {
          bool u0 = (lane & k) == 0;
          CAS_SHF(v0, j, u0) CAS_SHF(v1, j, u0) CAS_SHF(v2, j, u0) CAS_SHF(v3, j, u0)
        }
      }
      #pragma unroll
      for (int j = 32; j > 0; j >>= 1) {
        CAS_SHF(v0, j, true) CAS_SHF(v1, j, false) CAS_SHF(v2, j, true) CAS_SHF(v3, j, false)
      }
      CAS_REG(v0, v1, true) CAS_REG(v2, v3, false)
      #pragma unroll
      for (int j = 32; j > 0; j >>= 1) {
        CAS_SHF(v0, j, true) CAS_SHF(v1, j, true) CAS_SHF(v2, j, false) CAS_SHF(v3, j, false)
      }
      CAS_REG(v0, v2, true) CAS_REG(v1, v3, true)
      CAS_REG(v0, v1, true) CAS_REG(v2, v3, true)
      #pragma unroll
      for (int j = 32; j > 0; j >>= 1) {
        CAS_SHF(v0, j, true) CAS_SHF(v1, j, true) CAS_SHF(v2, j, true) CAS_SHF(v3, j, true)
      }
#undef CAS_REG
#undef CAS_SHF

      #pragma unroll
      for (int r = 0; r < 4; ++r) {
        u64 key = (r == 0) ? v0 : (r == 1) ? v1 : (r == 2) ? v2 : v3;
        int d = 255 - (r * 64 + lane);
        slo_s[d] = (u32)key;
        ssc_s[d] = sort2f((u32)(key >> 32));
      }
    }
    __syncthreads();

    // ---- gather boxes in sorted order ---------------------------------------
    if (tid < PK1) {
      u32 lo = slo_s[tid];
      u32 n = 0x7FFFu - ((lo >> 7) & 0x7FFFu);
      int cat = (int)(lo & 0x7Fu);
      const float* bp = boxes + ((size_t)b * NANCH + n) * 4;
      float4 ob = make_float4(bp[0], bp[1], bp[2], bp[3]);
      float off = 2.0f * (float)cat;
      float4 obo = make_float4(ob.x + off, ob.y + off, ob.z + off, ob.w + off);
      sorg_s[tid] = ob;
      sbo_s[tid] = obo;
      sar_s[tid] = fmaxf(obo.z - obo.x, 0.0f) * fmaxf(obo.w - obo.y, 0.0f);
    }
    __syncthreads();

    // ---- 256x256 mask, UPPER-TRIANGLE words only, column-swizzled -----------
    {
      int i = tid >> 2, w = tid & 3;
      u64 word = 0;
      if (w >= (i >> 6)) {           // bits j<=i never re-read by the scan
        float4 bi = sbo_s[i];
        float ai = sar_s[i];
        int j0 = w * 64, wsw = w << 1;
        for (int jj = 0; jj < 64; ++jj) {
          int jp = jj ^ wsw;
          float4 bj = sbo_s[j0 + jp];
          float lx = fmaxf(bi.x, bj.x), ly = fmaxf(bi.y, bj.y);
          float rx = fminf(bi.z, bj.z), ry = fminf(bi.w, bj.w);
          float iw = fmaxf(rx - lx, 0.0f), ih = fmaxf(ry - ly, 0.0f);
          float inter = iw * ih;
          float uni = fmaxf(ai + sar_s[j0 + jp] - inter, 1e-9f);
          if (inter > 0.5f * uni) word |= (1ull << jp);
        }
      }
      ovl.f.mk[i][w] = word;
    }
    __syncthreads();

    // ---- greedy scan, wave 0, 8-deep register prefetch ----------------------
    if (tid < 64) {
      bool l4 = lane < 4;
      u64 remv = 0;
      int kcnt = 0;
      u64 m0=0,m1=0,m2=0,m3=0,m4=0,m5=0,m6=0,m7=0;
      float s0, s1, s2, s3, s4, s5, s6, s7;
      if (l4) {
        m0 = ovl.f.mk[0][lane]; m1 = ovl.f.mk[1][lane]; m2 = ovl.f.mk[2][lane]; m3 = ovl.f.mk[3][lane];
        m4 = ovl.f.mk[4][lane]; m5 = ovl.f.mk[5][lane]; m6 = ovl.f.mk[6][lane]; m7 = ovl.f.mk[7][lane];
      }
      s0 = ssc_s[0]; s1 = ssc_s[1]; s2 = ssc_s[2]; s3 = ssc_s[3];
      s4 = ssc_s[4]; s5 = ssc_s[5]; s6 = ssc_s[6]; s7 = ssc_s[7];

#define PROC(D)                                                       \
      {                                                               \
        int i = base8 + (D);                                          \
        u64 wb = __shfl(remv, i >> 6);                                \
        bool sup = (wb >> (i & 63)) & 1ull;                           \
        if (!sup && s##D > SCORE_TH) {                                \
          if (lane == 0 && kcnt < MAX_OUT) keptI[kcnt] = i;           \
          if (l4) remv |= m##D;                                       \
          kcnt++;                                                     \
        }                                                             \
      }

      for (int base8 = 0; base8 < PK1; base8 += 8) {
        u64 t0=0,t1=0,t2=0,t3=0,t4=0,t5=0,t6=0,t7=0;
        float u0=0,u1=0,u2=0,u3=0,u4=0,u5=0,u6=0,u7=0;
        if (base8 + 8 < PK1) {
          int nb = base8 + 8;
          if (l4) {
            t0 = ovl.f.mk[nb+0][lane]; t1 = ovl.f.mk[nb+1][lane];
            t2 = ovl.f.mk[nb+2][lane]; t3 = ovl.f.mk[nb+3][lane];
            t4 = ovl.f.mk[nb+4][lane]; t5 = ovl.f.mk[nb+5][lane];
            t6 = ovl.f.mk[nb+6][lane]; t7 = ovl.f.mk[nb+7][lane];
          }
          u0 = ssc_s[nb+0]; u1 = ssc_s[nb+1]; u2 = ssc_s[nb+2]; u3 = ssc_s[nb+3];
          u4 = ssc_s[nb+4]; u5 = ssc_s[nb+5]; u6 = ssc_s[nb+6]; u7 = ssc_s[nb+7];
        }
        PROC(0) PROC(1) PROC(2) PROC(3) PROC(4) PROC(5) PROC(6) PROC(7)
        m0=t0; m1=t1; m2=t2; m3=t3; m4=t4; m5=t5; m6=t6; m7=t7;
        s0=u0; s1=u1; s2=u2; s3=u3; s4=u4; s5=u5; s6=u6; s7=u7;
        if (kcnt >= MAX_OUT) break;
      }
#undef PROC

      if (lane == 0) {
        s_kc = kcnt < MAX_OUT ? kcnt : MAX_OUT;
        s_ok = (kcnt >= MAX_OUT) && tieOK;
      }
    }
    __syncthreads();

    if (s_ok) {
      int kc = s_kc;
      float* out5 = out;
      float* ocat = out + BATCH * MAX_OUT * 5;
      for (int r = tid; r < MAX_OUT; r += 1024) {
        float* p = out5 + ((size_t)(b * MAX_OUT + r)) * 5;
        if (r < kc) {
          int i = keptI[r];
          float4 ob = sorg_s[i];
          p[0] = ob.x; p[1] = ob.y; p[2] = ob.z; p[3] = ob.w; p[4] = ssc_s[i];
          ocat[b * MAX_OUT + r] = (float)(slo_s[i] & 0x7Fu);
        } else {
          p[0] = 0.0f; p[1] = 0.0f; p[2] = 0.0f; p[3] = 0.0f; p[4] = 0.0f;
          ocat[b * MAX_OUT + r] = 0.0f;
        }
      }
      return;
    }
  }
  __syncthreads();

  // ================= INLINE exact-2048 fallback (never fires here) =========
  {
    if (tid == 0) { s_cnt = 0; s_tcnt = 0; }
    for (int i = tid; i < 4096; i += 1024) hist[i] = 0;
    __syncthreads();

    const uint4* bh4 = (const uint4*)(keyhi + (size_t)b * NANCH);
    uint4 hk[8];
    #pragma unroll
    for (int j = 0; j < 8; ++j) hk[j] = bh4[tid + j * 1024];

#define ELEM(j, c) ((c) == 0 ? hk[j].x : (c) == 1 ? hk[j].y : (c) == 2 ? hk[j].z : hk[j].w)
    #pragma unroll
    for (int j = 0; j < 8; ++j) {
      #pragma unroll
      for (int c = 0; c < 4; ++c) {
        u32 d = ELEM(j, c) >> 24;
        u64 todo = ~0ull;
        while (todo) {
          int src = __ffsll((unsigned long long)todo) - 1;
          u32 dd = __shfl(d, src);
          u64 match = __ballot(d == dd);
          if (lane == src) atomicAdd(&hist[dd], (u32)__popcll(match));
          todo &= ~match;
        }
      }
    }
    __syncthreads();
    int D1, n1;
    scan_digit_fast<256>(hist, PRE_K, sbuf, tid, &D1, &n1);

    for (int i = tid; i < 4096; i += 1024) hist[i] = 0;
    __syncthreads();
    u32 p1 = (u32)D1;
    #pragma unroll
    for (int j = 0; j < 8; ++j) {
      #pragma unroll
      for (int c = 0; c < 4; ++c) {
        u32 h = ELEM(j, c);
        if ((h >> 24) == p1) atomicAdd(&hist[(h >> 12) & 0xFFF], 1u);
      }
    }
    __syncthreads();
    int D2, n2;
    scan_digit_fast<4096>(hist, n1, sbuf, tid, &D2, &n2);

    for (int i = tid; i < 4096; i += 1024) hist[i] = 0;
    __syncthreads();
    u32 p2 = (p1 << 12) | (u32)D2;
    #pragma unroll
    for (int j = 0; j < 8; ++j) {
      #pragma unroll
      for (int c = 0; c < 4; ++c) {
        u32 h = ELEM(j, c);
        if ((h >> 12) == p2) atomicAdd(&hist[h & 0xFFF], 1u);
      }
    }
    __syncthreads();
    int D3, n3;
    scan_digit_fast<4096>(hist, n2, sbuf, tid, &D3, &n3);

    u32 S32 = (p2 << 12) | (u32)D3;
    int need3 = n3;

    #pragma unroll
    for (int j = 0; j < 8; ++j) {
      #pragma unroll
      for (int c = 0; c < 4; ++c) {
        u32 h = ELEM(j, c);
        u32 n = (u32)(4 * tid + 4096 * j + c);
        u64 k = ((u64)h << 32) | (u64)(0xFFFFFFFFu - n);
        bool gt = h > S32;
        u64 m = __ballot(gt);
        u32 wbase = 0;
        if (lane == 0 && m) wbase = atomicAdd(&s_cnt, (u32)__popcll(m));
        wbase = __shfl(wbase, 0);
        if (gt) {
          u32 pos = wbase + (u32)__popcll(m & ((1ull << lane) - 1));
          if (pos < PRE_K) ovl.selk2[pos] = k;
        }
        if (h == S32) {
          u32 tp = atomicAdd(&s_tcnt, 1u);
          if (tp < 128) ties[tp] = k;
        }
      }
    }
#undef ELEM
    __syncthreads();

    {
      int nt = (int)s_tcnt; if (nt > 128) nt = 128;
      int base = (int)s_cnt;
      if (tid < nt) {
        u64 my = ties[tid];
        int r = 0;
        for (int j = 0; j < nt; ++j) r += (ties[j] > my);
        if (r < need3 && base + r < PRE_K) ovl.selk2[base + r] = my;
      }
    }
    __syncthreads();

    for (int k = 2; k <= PRE_K; k <<= 1) {
      for (int j = k >> 1; j > 0; j >>= 1) {
        for (int idx = tid; idx < PRE_K; idx += 1024) {
          int ixj = idx ^ j;
          if (ixj > idx) {
            u64 a = ovl.selk2[idx], cc = ovl.selk2[ixj];
            bool up = ((idx & k) == 0);
            if ((a > cc) == up) { ovl.selk2[idx] = cc; ovl.selk2[ixj] = a; }
          }
        }
        __syncthreads();
      }
    }

    // emit candidate records to global
    for (int r = tid; r < PRE_K; r += 1024) {
      u64 my = ovl.selk2[PRE_K - 1 - r];
      u32 n = 0xFFFFFFFFu - (u32)(my & 0xFFFFFFFFu);
      float s = sort2f((u32)(my >> 32));
      int cat = (int)cats[(size_t)b * NANCH + n];
      const float* bp = boxes + ((size_t)b * NANCH + n) * 4;
      float4 ob = make_float4(bp[0], bp[1], bp[2], bp[3]);
      float off = 2.0f * (float)cat;
      float4 obo = make_float4(ob.x + off, ob.y + off, ob.z + off, ob.w + off);
      int o = b * PRE_K + r;
      candOff[o] = obo;
      candOrig[o] = ob;
      candScore[o] = s;
      candCat[o] = cat;
    }
    __threadfence();
    __syncthreads();

    // phase B: 2048x2048 upper-triangle mask -> global
    {
      float4* sb = (float4*)ovl.selk2;   // 16 KB = 1024 boxes
      float* sarea = (float*)hist;       // 4 KB
      for (int half = 0; half < 2; ++half) {
        for (int j = tid; j < 1024; j += 1024) {
          float4 v = candOff[b * PRE_K + half * 1024 + j];
          sb[j] = v;
          sarea[j] = fmaxf(v.z - v.x, 0.0f) * fmaxf(v.w - v.y, 0.0f);
        }
        __syncthreads();
        for (int it = 0; it < 64; ++it) {
          int i = it * 32 + (tid >> 5);
          int wl = tid & 31;
          if (wl < 16) {
            int gw = half * 16 + wl;
            float4 bi = candOff[b * PRE_K + i];
            float ai = fmaxf(bi.z - bi.x, 0.0f) * fmaxf(bi.w - bi.y, 0.0f);
            u64 word = 0;
            if (gw >= (i >> 6)) {
              int j0 = wl * 64;
              for (int jj = 0; jj < 64; ++jj) {
                float4 bj = sb[j0 + jj];
                float lx = fmaxf(bi.x, bj.x), ly = fmaxf(bi.y, bj.y);
                float rx = fminf(bi.z, bj.z), ry = fminf(bi.w, bj.w);
                float iw = fmaxf(rx - lx, 0.0f), ih = fmaxf(ry - ly, 0.0f);
                float inter = iw * ih;
                float uni = fmaxf(ai + sarea[j0 + jj] - inter, 1e-9f);
                if (inter > 0.5f * uni) word |= (1ull << jj);
              }
            }
            mask[((size_t)(b * PRE_K + i)) * 32 + gw] = word;
          }
        }
        __syncthreads();
      }
    }
    __threadfence();
    __syncthreads();

    // phase C: greedy scan (wave 0) + output
    {
      float* ssc = (float*)hist;
      for (int j = tid; j < PRE_K; j += 1024) ssc[j] = candScore[b * PRE_K + j];
      __syncthreads();

      if (tid < 64) {
        const u64* mrow = mask + (size_t)b * PRE_K * 32;
        int wsel = lane & 31;
        bool lo32 = lane < 32;
        u64 remv = 0;
        int cnt2 = 0;
        u64 rowCur = lo32 ? mrow[wsel] : 0;
        for (int i = 0; i < PRE_K && cnt2 < MAX_OUT; ++i) {
          u64 rowNxt = (i + 1 < PRE_K && lo32) ? mrow[(size_t)(i + 1) * 32 + wsel] : 0ull;
          u64 wb = __shfl(remv, i >> 6);
          bool sup = (wb >> (i & 63)) & 1ull;
          if (!sup && ssc[i] > SCORE_TH) {
            if (lane == 0) keptI[cnt2] = i;
            if (lo32) remv |= rowCur;
            cnt2++;
          }
          rowCur = rowNxt;
        }
        if (lane == 0) sbuf[0] = (u32)(cnt2 < MAX_OUT ? cnt2 : MAX_OUT);
      }
      __syncthreads();

      int kc = (int)sbuf[0];
      float* out5 = out;
      float* ocat = out + BATCH * MAX_OUT * 5;
      for (int r = tid; r < MAX_OUT; r += 1024) {
        float* p = out5 + ((size_t)(b * MAX_OUT + r)) * 5;
        if (r < kc) {
          int i = keptI[r];
          float4 ob = candOrig[b * PRE_K + i];
          p[0] = ob.x; p[1] = ob.y; p[2] = ob.z; p[3] = ob.w; p[4] = ssc[i];
          ocat[b * MAX_OUT + r] = (float)candCat[b * PRE_K + i];
        } else {
          p[0] = 0.0f; p[1] = 0.0f; p[2] = 0.0f; p[3] = 0.0f; p[4] = 0.0f;
          ocat[b * MAX_OUT + r] = 0.0f;
        }
      }
    }
  }
}

extern "C" void kernel_launch(void* const* d_in, const int* in_sizes, int n_in,
                              void* d_out, int out_size, void* d_ws, size_t ws_size,
                              hipStream_t stream) {
  const float* boxes = (const float*)d_in[0];
  const float* confs = (const float*)d_in[1];
  float* out = (float*)d_out;
  char* ws = (char*)d_ws;

  const size_t OFF_KHI  = 0;                            // 1 MB
  const size_t OFF_CATS = (size_t)1 << 20;              // 256 KB
  const size_t OFF_CNT  = OFF_CATS + (256u << 10);      // 4 KB
  const size_t OFF_CB   = OFF_CNT + 4096;               // 512 KB
  const size_t OFF_COFF = OFF_CB + (size_t)4096 * SLOTS * 8;
  const size_t OFF_CORG = OFF_COFF + (256u << 10);
  const size_t OFF_CSC  = OFF_CORG + (256u << 10);
  const size_t OFF_CCAT = OFF_CSC + (64u << 10);
  const size_t OFF_MASK = OFF_CCAT + (64u << 10);       // 4 MB

  u32* keyhi   = (u32*)(ws + OFF_KHI);
  u8* cats     = (u8*)(ws + OFF_CATS);
  u8* cntA     = (u8*)(ws + OFF_CNT);
  u64* candBuf = (u64*)(ws + OFF_CB);
  float4* cOff = (float4*)(ws + OFF_COFF);
  float4* cOrg = (float4*)(ws + OFF_CORG);
  float* cSc   = (float*)(ws + OFF_CSC);
  int* cCat    = (int*)(ws + OFF_CCAT);
  u64* mask    = (u64*)(ws + OFF_MASK);

  k_score<<<BATCH * NANCH / 64, 256, 0, stream>>>(confs, keyhi, cats, candBuf, cntA);
  k_sel<<<BATCH, 1024, 0, stream>>>(candBuf, cntA, keyhi, cats, boxes,
                                    cOff, cOrg, cSc, cCat, mask, out);
}